// Round 18
// baseline (1023.428 us; speedup 1.0000x reference)
//
#include <hip/hip_runtime.h>
#include <cfloat>

namespace {

constexpr int Bb    = 4;
constexpr int Nn    = 4096;
constexpr int Cc    = 96;
constexpr int Ll    = 4;           // hops+1 slots
constexpr int NPTS  = Bb * Nn;     // 16384
constexpr int KP    = 100;         // padded LDS row stride (floats) for fp32 gemm
constexpr int CS    = 4;           // column splits of the db dimension
constexpr int TK    = 10;          // per-lane candidates (recall bound: 8)
constexpr int NCROW = CS * 4 * TK; // 160 candidates per row
constexpr int LP    = 104;         // bf16 LDS row pitch (208 B)
constexpr int NSEL  = 24;          // np-rescored survivors of the fast-key merge

typedef __attribute__((ext_vector_type(8))) short bf16x8;
typedef __attribute__((ext_vector_type(4))) float f32x4;

// RNE fp32 -> bf16 (candidate ranking only)
__device__ inline ushort f2bf(float x) {
    unsigned u = __float_as_uint(x);
    return (ushort)((u + 0x7FFF + ((u >> 16) & 1)) >> 16);
}

// lexicographic (value asc, index asc) sorted-insert into top-T
template<int T>
__device__ inline void lexins(float v, int vi, float (&bd)[T], int (&bi)[T]) {
    if (v < bd[T - 1] || (v == bd[T - 1] && vi < bi[T - 1])) {
        #pragma unroll
        for (int t = 0; t < T; ++t) {
            if (v < bd[t] || (v == bd[t] && vi < bi[t])) {
                float tv = bd[t]; bd[t] = v;  v  = tv;
                int   ti = bi[t]; bi[t] = vi; vi = ti;
            }
        }
    }
}

// ---- fused: (optional xyz->A32 slot0 copy) + np-mimic sq (pairwise-8) + bf16 cvt ----
template<bool COPY>
__global__ __launch_bounds__(64) void sqcvt_kernel(const float* __restrict__ src0,
                                                   float* __restrict__ A32,
                                                   float* __restrict__ sqnp,
                                                   ushort* __restrict__ A16, int h) {
    const int p = blockIdx.x * 64 + threadIdx.x;
    const float4* xs = reinterpret_cast<const float4*>(
        COPY ? src0 + (size_t)p * Cc : src0 + (size_t)(p * Ll + h) * Cc);
    float4 x[24];
    #pragma unroll
    for (int i = 0; i < 24; ++i) x[i] = xs[i];
    if (COPY) {
        float4* d = reinterpret_cast<float4*>(A32 + (size_t)p * Ll * Cc);
        #pragma unroll
        for (int i = 0; i < 24; ++i) d[i] = x[i];
    }
    // numpy pairwise-8 tree over fl(x*x)
    float r[8];
    r[0] = __fmul_rn(x[0].x, x[0].x); r[1] = __fmul_rn(x[0].y, x[0].y);
    r[2] = __fmul_rn(x[0].z, x[0].z); r[3] = __fmul_rn(x[0].w, x[0].w);
    r[4] = __fmul_rn(x[1].x, x[1].x); r[5] = __fmul_rn(x[1].y, x[1].y);
    r[6] = __fmul_rn(x[1].z, x[1].z); r[7] = __fmul_rn(x[1].w, x[1].w);
    #pragma unroll
    for (int g = 1; g < 12; ++g) {
        float4 va = x[2 * g], vb = x[2 * g + 1];
        r[0] = __fadd_rn(r[0], __fmul_rn(va.x, va.x));
        r[1] = __fadd_rn(r[1], __fmul_rn(va.y, va.y));
        r[2] = __fadd_rn(r[2], __fmul_rn(va.z, va.z));
        r[3] = __fadd_rn(r[3], __fmul_rn(va.w, va.w));
        r[4] = __fadd_rn(r[4], __fmul_rn(vb.x, vb.x));
        r[5] = __fadd_rn(r[5], __fmul_rn(vb.y, vb.y));
        r[6] = __fadd_rn(r[6], __fmul_rn(vb.z, vb.z));
        r[7] = __fadd_rn(r[7], __fmul_rn(vb.w, vb.w));
    }
    float L = __fadd_rn(__fadd_rn(r[0], r[1]), __fadd_rn(r[2], r[3]));
    float R = __fadd_rn(__fadd_rn(r[4], r[5]), __fadd_rn(r[6], r[7]));
    sqnp[p] = __fadd_rn(L, R);
    #pragma unroll
    for (int j = 0; j < 12; ++j) {
        float4 v0 = x[2 * j], v1 = x[2 * j + 1];
        uint4 o;
        o.x = (unsigned)f2bf(v0.x) | ((unsigned)f2bf(v0.y) << 16);
        o.y = (unsigned)f2bf(v0.z) | ((unsigned)f2bf(v0.w) << 16);
        o.z = (unsigned)f2bf(v1.x) | ((unsigned)f2bf(v1.y) << 16);
        o.w = (unsigned)f2bf(v1.z) | ((unsigned)f2bf(v1.w) << 16);
        *reinterpret_cast<uint4*>(A16 + (size_t)p * 96 + j * 8) = o;
    }
}

// ---- MFMA candidate pass: CS=4 (16 waves/CU of work), qt/klds LDS union
// (47.6 KB -> 3 blocks/CU), chunk=64 double-buffer, PACKED-KEY scan.
// acc init = -sq/2 -> accumulator holds s = dot - sq/2 (d2 asc == s DESC).
// Key = (ordered_uint(v) & ~511) | (511 - stream_pos); bubble insert is a
// max/min pair per step. grid (NPTS/64, CS), block 256.
__global__ __launch_bounds__(256) void knn_mfma_kernel(const ushort* __restrict__ A16,
                                                       const float* __restrict__ sqnp,
                                                       int* __restrict__ cand,
                                                       unsigned* __restrict__ fkey) {
    __shared__ alignas(16) char uqk[20480];   // union: qt (13312 B) then klds (20480 B)
    __shared__ ushort dbt[2][64 * LP];        // 26624 B
    __shared__ float  sqf[2][64];             //   512 B
    ushort* qt   = (ushort*)uqk;
    float*  klds = (float*)uqk;

    const int q0    = blockIdx.x * 64;
    const int cs    = blockIdx.y;
    const int pbase = (q0 >> 12) << 12;
    const int col0  = cs * (Nn / CS);
    const int tid   = threadIdx.x;
    const int w     = tid >> 6;
    const int l     = tid & 63;
    constexpr int NCH = (Nn / CS) / 64;       // 16 chunks

    {
        int r = tid >> 2, q = tid & 3;
        const uint4* s = reinterpret_cast<const uint4*>(A16 + (size_t)(q0 + r) * 96 + q * 24);
        uint4* d = reinterpret_cast<uint4*>(qt + r * LP + q * 24);
        d[0] = s[0]; d[1] = s[1]; d[2] = s[2];
        const uint4* s2 = reinterpret_cast<const uint4*>(
            A16 + (size_t)(pbase + col0 + r) * 96 + q * 24);
        uint4* d2 = reinterpret_cast<uint4*>(dbt[0] + r * LP + q * 24);
        d2[0] = s2[0]; d2[1] = s2[1]; d2[2] = s2[2];
    }
    if (tid < 64) sqf[0][tid] = -0.5f * sqnp[pbase + col0 + tid];
    __syncthreads();

    const int qrow = w * 16 + (l & 15);
    const int koff = (l >> 4) * 8;
    const int lb4  = (l >> 4) * 4;
    bf16x8 bq[3];
    #pragma unroll
    for (int s = 0; s < 3; ++s)
        bq[s] = *reinterpret_cast<const bf16x8*>(qt + qrow * LP + koff + 32 * s);
    __syncthreads();   // qt reads done before klds (aliased) is written

    // packed top-TK (descending). 0x00800000 = packed(-FLT_MAX) -> always replaced.
    unsigned bd[TK];
    #pragma unroll
    for (int t = 0; t < TK; ++t) bd[t] = 0x00800000u;
    float kd = -FLT_MAX;

    for (int c = 0; c < NCH; ++c) {
        const int buf = c & 1;
        if (c + 1 < NCH) {
            int r = tid >> 2, q = tid & 3;
            const uint4* s = reinterpret_cast<const uint4*>(
                A16 + (size_t)(pbase + col0 + (c + 1) * 64 + r) * 96 + q * 24);
            uint4* d = reinterpret_cast<uint4*>(dbt[buf ^ 1] + r * LP + q * 24);
            d[0] = s[0]; d[1] = s[1]; d[2] = s[2];
            if (tid < 64) sqf[buf ^ 1][tid] = -0.5f * sqnp[pbase + col0 + (c + 1) * 64 + tid];
        }

        f32x4 acc[4];
        #pragma unroll
        for (int sub = 0; sub < 4; ++sub) {
            acc[sub] = *reinterpret_cast<const f32x4*>(&sqf[buf][sub * 16 + lb4]);
            #pragma unroll
            for (int s = 0; s < 3; ++s) {
                bf16x8 a = *reinterpret_cast<const bf16x8*>(
                    dbt[buf] + (sub * 16 + (l & 15)) * LP + koff + 32 * s);
                acc[sub] = __builtin_amdgcn_mfma_f32_16x16x32_bf16(a, bq[s], acc[sub], 0, 0, 0);
            }
        }

        unsigned mask = 0;
        #pragma unroll
        for (int sub = 0; sub < 4; ++sub) {
            float m = fmaxf(fmaxf(acc[sub][0], acc[sub][1]),
                            fmaxf(acc[sub][2], acc[sub][3]));
            if (m > kd) {
                *reinterpret_cast<f32x4*>(&klds[tid * 20 + sub * 4]) = acc[sub];
                unsigned mb = (acc[sub][0] > kd ? 1u : 0u) |
                              (acc[sub][1] > kd ? 2u : 0u) |
                              (acc[sub][2] > kd ? 4u : 0u) |
                              (acc[sub][3] > kd ? 8u : 0u);
                mask |= mb << (sub * 4);
            }
        }
        while (mask) {
            int s = __builtin_ctz(mask); mask &= mask - 1;
            float v = klds[tid * 20 + s];
            if (v > kd) {
                unsigned b   = __float_as_uint(v);
                unsigned key = ((b ^ (unsigned)(((int)b >> 31) | 0x80000000)) & ~511u)
                               | (511u - (unsigned)(c * 16 + s));
                #pragma unroll
                for (int t = 0; t < TK; ++t) {
                    unsigned hi = key > bd[t] ? key : bd[t];
                    key         = key > bd[t] ? bd[t] : key;
                    bd[t] = hi;
                }
                unsigned u = bd[TK - 1] & ~511u;
                kd = __uint_as_float((u & 0x80000000u) ? (u ^ 0x80000000u) : ~u);
            }
        }
        __syncthreads();
    }

    const int qg = q0 + qrow;
    const size_t obase = (size_t)qg * NCROW + (cs * 4 + (l >> 4)) * TK;
    #pragma unroll
    for (int t = 0; t < TK; ++t) {
        unsigned key = bd[t];
        int pos = 511 - (int)(key & 511u);
        int c2 = pos >> 4, s2 = pos & 15;
        cand[obase + t] = col0 + c2 * 64 + ((s2 >> 2) << 4) + lb4 + (s2 & 3);
        fkey[obase + t] = key;
    }
}

// ---- np-exact rescore with gather-free packed-key prefilter + np mean ----
// 16 sorted streams of TK=10; merge -> top-24; np-exact rescore survivors.
// block 256 = 32 queries x 8 subs; grid NPTS/32.
__global__ __launch_bounds__(256) void rescore_mean_kernel(const float* __restrict__ A32,
                                                           const float* __restrict__ sqnp,
                                                           const int* __restrict__ cand,
                                                           const unsigned* __restrict__ fkey,
                                                           float* __restrict__ nb, int h) {
    __shared__ unsigned kly[32][164];  // packed keys (16 sorted streams of 10)
    __shared__ int      cly[32][164];  // candidate indices
    __shared__ int      m24[32][NSEL];
    __shared__ float    s24[32][NSEL];
    __shared__ int      sidx[32][8];
    const int tid  = threadIdx.x;
    const int qloc = tid >> 3, sub = tid & 7;
    const int p    = blockIdx.x * 32 + qloc;
    const int base = (p >> 12) << 12;

    // ---- phase 0: stream pairs into LDS (20 per sub = 5 uint4) ----
    {
        const uint4* fs = reinterpret_cast<const uint4*>(fkey + (size_t)p * NCROW + sub * 20);
        const int4*  is = reinterpret_cast<const int4*>(cand + (size_t)p * NCROW + sub * 20);
        #pragma unroll
        for (int m = 0; m < 5; ++m) {
            *reinterpret_cast<uint4*>(&kly[qloc][sub * 20 + m * 4]) = fs[m];
            *reinterpret_cast<int4*>(&cly[qloc][sub * 20 + m * 4])  = is[m];
        }
    }
    __syncthreads();

    // ---- phase 0b: top-24 by (packed key DESC, idx ASC) — 16-way list merge ----
    if (sub == 0) {
        unsigned long long hp = 0;
        #pragma unroll 1
        for (int t = 0; t < NSEL; ++t) {
            unsigned bk = 0; int bs = 0, bidx = 0x7fffffff; bool any = false;
            #pragma unroll
            for (int s = 0; s < 16; ++s) {
                int hs = (int)((hp >> (4 * s)) & 15);
                if (hs < TK) {
                    unsigned k = kly[qloc][s * TK + hs];
                    int      i = cly[qloc][s * TK + hs];
                    if (!any || k > bk || (k == bk && i < bidx)) {
                        bk = k; bs = s; bidx = i; any = true;
                    }
                }
            }
            m24[qloc][t] = bidx;
            hp += 1ull << (4 * bs);
        }
    }
    __syncthreads();

    // ---- phase 1: np-exact rescore of the 24 survivors (3 per sub) ----
    {
        float4 xnr[24];
        const float4* xs = reinterpret_cast<const float4*>(A32 + (size_t)(p * Ll + h) * Cc);
        #pragma unroll
        for (int i = 0; i < 24; ++i) xnr[i] = xs[i];
        const float sqn = sqnp[p];
        #pragma unroll
        for (int c = 0; c < NSEL / 8; ++c) {
            int m = m24[qloc][sub * (NSEL / 8) + c];
            const float4* xm = reinterpret_cast<const float4*>(
                A32 + (size_t)((base + m) * Ll + h) * Cc);
            // np einsum dot: SSE SOP — 4-lane mul+add accumulators, hadd combine
            float l0 = 0.f, l1 = 0.f, l2 = 0.f, l3 = 0.f;
            #pragma unroll
            for (int t = 0; t < 24; ++t) {
                float4 a = xnr[t], b = xm[t];
                l0 = __fadd_rn(l0, __fmul_rn(a.x, b.x));
                l1 = __fadd_rn(l1, __fmul_rn(a.y, b.y));
                l2 = __fadd_rn(l2, __fmul_rn(a.z, b.z));
                l3 = __fadd_rn(l3, __fmul_rn(a.w, b.w));
            }
            float dot = __fadd_rn(__fadd_rn(l0, l1), __fadd_rn(l2, l3));
            // np: d2 = fl(fl(sq_n + sq_m) - fl(2*dot))
            s24[qloc][sub * (NSEL / 8) + c] =
                __fsub_rn(__fadd_rn(sqn, sqnp[base + m]), __fmul_rn(2.0f, dot));
        }
    }
    __syncthreads();

    // ---- phase 2: stable top-8 by (d2, idx) — lax.top_k tie semantics ----
    if (sub == 0) {
        float sd[8]; int si[8];
        #pragma unroll
        for (int t = 0; t < 8; ++t) { sd[t] = FLT_MAX; si[t] = 0x7fffffff; }
        #pragma unroll 1
        for (int c = 0; c < NSEL; ++c) lexins<8>(s24[qloc][c], m24[qloc][c], sd, si);
        #pragma unroll
        for (int t = 0; t < 8; ++t) sidx[qloc][t] = si[t];
    }
    __syncthreads();

    // ---- phase 3: np-mimic mean (pairwise-8 tree, x0.125) ----
    {
        float4 rv[8][3];
        #pragma unroll
        for (int k = 0; k < 8; ++k) {
            const float4* rs = reinterpret_cast<const float4*>(
                A32 + (size_t)((base + sidx[qloc][k]) * Ll + h) * Cc + sub * 12);
            rv[k][0] = rs[0]; rv[k][1] = rs[1]; rv[k][2] = rs[2];
        }
        float4* dst = reinterpret_cast<float4*>(nb + (size_t)p * Cc + sub * 12);
        #pragma unroll
        for (int g = 0; g < 3; ++g) {
            float4 o;
            #define NPMEAN(comp) { \
                float L_ = __fadd_rn(__fadd_rn(rv[0][g].comp, rv[1][g].comp), \
                                     __fadd_rn(rv[2][g].comp, rv[3][g].comp)); \
                float R_ = __fadd_rn(__fadd_rn(rv[4][g].comp, rv[5][g].comp), \
                                     __fadd_rn(rv[6][g].comp, rv[7][g].comp)); \
                o.comp = __fmul_rn(__fadd_rn(L_, R_), 0.125f); }
            NPMEAN(x) NPMEAN(y) NPMEAN(z) NPMEAN(w)
            #undef NPMEAN
            dst[g] = o;
        }
    }
}

// ---- np-mimic MLP GEMM: W staged in LDS once per 16 rows; np FMA chain ----
template<int K, bool LEAKY>
__global__ __launch_bounds__(256) void npgemm_kernel(const float* __restrict__ A,
                                                     const float* __restrict__ W,
                                                     const float* __restrict__ bias,
                                                     float* __restrict__ out,
                                                     int N, int ostride) {
    constexpr int PW = (K == 96) ? 100 : 196;
    __shared__ float w_t[64 * PW];
    const int tx = threadIdx.x, ty = threadIdx.y;
    const int col0 = blockIdx.x * 64;
    const int j = col0 + tx;
    const int i0 = blockIdx.y * 16 + ty * 4;
    {
        int tid = ty * 64 + tx;
        int r = tid >> 2, q = tid & 3;
        constexpr int G = K / 16;
        float4* dst = reinterpret_cast<float4*>(&w_t[r * PW]) + q * G;
        if (col0 + r < N) {
            const float4* src = reinterpret_cast<const float4*>(
                W + (size_t)(col0 + r) * K) + q * G;
            #pragma unroll
            for (int m = 0; m < G; ++m) dst[m] = src[m];
        } else {
            #pragma unroll
            for (int m = 0; m < G; ++m) dst[m] = float4{0.f, 0.f, 0.f, 0.f};
        }
    }
    __syncthreads();
    if (j < N) {
        #pragma unroll
        for (int rr = 0; rr < 4; ++rr) {
            const float* a = A + (size_t)(i0 + rr) * K;
            float acc = 0.f;
            #pragma unroll
            for (int k4 = 0; k4 < K / 4; ++k4) {
                float4 wv = *reinterpret_cast<const float4*>(&w_t[tx * PW + k4 * 4]);
                float4 av = *reinterpret_cast<const float4*>(a + k4 * 4);
                acc = __builtin_fmaf(av.x, wv.x, acc);
                acc = __builtin_fmaf(av.y, wv.y, acc);
                acc = __builtin_fmaf(av.z, wv.z, acc);
                acc = __builtin_fmaf(av.w, wv.w, acc);
            }
            float v = __fadd_rn(acc, bias[j]);
            if (LEAKY) v = v > 0.f ? v : __fmul_rn(0.2f, v);
            out[(size_t)(i0 + rr) * ostride + j] = v;
        }
    }
}

// ---- swizzled fp32 tile staging for value-path gemm ----
__device__ inline void stage_row(const float* __restrict__ src, float* __restrict__ tile,
                                 int r, int q) {
    const int s = (r >> 2) & 7;
    #pragma unroll
    for (int m = 0; m < 6; ++m) {
        int g = q * 6 + m;
        float4 v = reinterpret_cast<const float4*>(src)[g];
        *reinterpret_cast<float4*>(&tile[r * KP + ((g ^ s) << 2)]) = v;
    }
}

// ---------------- fast fp32 GEMM (value path): out = Ain @ W^T + bias ----------------
template<int K>
__global__ __launch_bounds__(256) void gemm_kernel(const float* __restrict__ Ain,
                                                   const float* __restrict__ W,
                                                   const float* __restrict__ bias,
                                                   float* __restrict__ out,
                                                   int Nout, int out_stride) {
    __shared__ float a_t[64 * KP];
    __shared__ float w_t[64 * KP];
    const int row0 = blockIdx.x * 64;
    const int col0 = blockIdx.y * 64;
    const int tid  = threadIdx.x;
    const int tx   = tid & 15;
    const int ty   = tid >> 4;

    float acc[4][4] = {};
    for (int kt = 0; kt < K; kt += 96) {
        __syncthreads();
        {
            int r = tid >> 2, q = tid & 3;
            stage_row(Ain + (size_t)(row0 + r) * K + kt, a_t, r, q);
            if (col0 + r < Nout) {
                stage_row(W + (size_t)(col0 + r) * K + kt, w_t, r, q);
            } else {
                const int s = (r >> 2) & 7;
                #pragma unroll
                for (int m = 0; m < 6; ++m) {
                    int g = q * 6 + m;
                    *reinterpret_cast<float4*>(&w_t[r * KP + ((g ^ s) << 2)]) =
                        float4{0.f, 0.f, 0.f, 0.f};
                }
            }
        }
        __syncthreads();
        const int sa = ty & 7, sb = tx & 7;
        #pragma unroll 4
        for (int k4 = 0; k4 < 24; ++k4) {
            float4 av[4], bv[4];
            const int ga = (k4 ^ sa) << 2, gb = (k4 ^ sb) << 2;
            #pragma unroll
            for (int i = 0; i < 4; ++i)
                av[i] = *reinterpret_cast<const float4*>(&a_t[(ty * 4 + i) * KP + ga]);
            #pragma unroll
            for (int j = 0; j < 4; ++j)
                bv[j] = *reinterpret_cast<const float4*>(&w_t[(tx * 4 + j) * KP + gb]);
            #pragma unroll
            for (int i = 0; i < 4; ++i)
                #pragma unroll
                for (int j = 0; j < 4; ++j)
                    acc[i][j] += av[i].x * bv[j].x + av[i].y * bv[j].y +
                                 av[i].z * bv[j].z + av[i].w * bv[j].w;
        }
    }
    #pragma unroll
    for (int i = 0; i < 4; ++i) {
        int row = row0 + ty * 4 + i;
        #pragma unroll
        for (int j = 0; j < 4; ++j) {
            int col = col0 + tx * 4 + j;
            if (col < Nout)
                out[(size_t)row * out_stride + col] = acc[i][j] + bias[col];
        }
    }
}

// ---- Wvo fold precompute: Wvo[i][h*96+j] = sum_k opw[i][h*32+k]*Wv[h*32+k][j];
// b2o[i] = opb[i] + sum_k opw[i][k]*bv[k].  (Wv = ipw rows 192..287, bv = ipb+192.)
__global__ __launch_bounds__(256) void wvo_kernel(const float* __restrict__ ipw,
                                                  const float* __restrict__ ipb,
                                                  const float* __restrict__ opw,
                                                  const float* __restrict__ opb,
                                                  float* __restrict__ wvo,
                                                  float* __restrict__ b2o) {
    int t = blockIdx.x * 256 + threadIdx.x;          // 96*288 outs
    if (t < 96 * 288) {
        int i = t / 288, hj = t - i * 288;
        int hh = hj / 96, j = hj - hh * 96;
        float acc = 0.f;
        #pragma unroll 8
        for (int k = 0; k < 32; ++k)
            acc = __builtin_fmaf(opw[i * 96 + hh * 32 + k],
                                 ipw[(size_t)(192 + hh * 32 + k) * 96 + j], acc);
        wvo[(size_t)i * 288 + hj] = acc;
    }
    if (t < 96) {
        float acc = opb[t];
        #pragma unroll 8
        for (int k = 0; k < 96; ++k)
            acc = __builtin_fmaf(opw[t * 96 + k], ipb[192 + k], acc);
        b2o[t] = acc;
    }
}

// ---- per-(point, head) attention mix: softmax(q k^T) mean over tokens applied
// directly to the INPUT features x (V/out-proj folded into Wvo downstream).
// qk: [65536][192] (q|k per stacked row). out: xmixs[point][head*96 + j].
__global__ __launch_bounds__(64) void attnmix_kernel(const float* __restrict__ qk,
                                                     const float* __restrict__ A32,
                                                     float* __restrict__ xmixs) {
    int t  = blockIdx.x * 64 + threadIdx.x;   // 16384*3
    int p  = t / 3;
    int hh = t - p * 3;
    const float* qb = qk + (size_t)p * 4 * 192 + hh * 32;
    const float* kb = qb + 96;

    float sc[4][4] = {};
    #pragma unroll
    for (int d = 0; d < 32; d += 4) {
        float4 qv[4], kv[4];
        #pragma unroll
        for (int l2 = 0; l2 < 4; ++l2) {
            qv[l2] = *reinterpret_cast<const float4*>(qb + l2 * 192 + d);
            kv[l2] = *reinterpret_cast<const float4*>(kb + l2 * 192 + d);
        }
        #pragma unroll
        for (int l2 = 0; l2 < 4; ++l2)
            #pragma unroll
            for (int m = 0; m < 4; ++m)
                sc[l2][m] += qv[l2].x * kv[m].x + qv[l2].y * kv[m].y +
                             qv[l2].z * kv[m].z + qv[l2].w * kv[m].w;
    }
    const float scale = 0.17677669529663687f;   // 1/sqrt(32)
    float am[4] = {0.f, 0.f, 0.f, 0.f};
    #pragma unroll
    for (int l2 = 0; l2 < 4; ++l2) {
        float s0 = sc[l2][0] * scale, s1 = sc[l2][1] * scale;
        float s2 = sc[l2][2] * scale, s3 = sc[l2][3] * scale;
        float mx = fmaxf(fmaxf(s0, s1), fmaxf(s2, s3));
        float e0 = expf(s0 - mx), e1 = expf(s1 - mx);
        float e2 = expf(s2 - mx), e3 = expf(s3 - mx);
        float inv = 1.f / (e0 + e1 + e2 + e3);
        am[0] += e0 * inv; am[1] += e1 * inv; am[2] += e2 * inv; am[3] += e3 * inv;
    }
    am[0] *= 0.25f; am[1] *= 0.25f; am[2] *= 0.25f; am[3] *= 0.25f;
    const float* xb = A32 + (size_t)p * 4 * 96;
    float* dst = xmixs + (size_t)p * 288 + hh * 96;
    #pragma unroll
    for (int d = 0; d < 96; d += 4) {
        float4 o = {0.f, 0.f, 0.f, 0.f};
        #pragma unroll
        for (int m = 0; m < 4; ++m) {
            float4 v = *reinterpret_cast<const float4*>(xb + m * 96 + d);
            o.x += am[m] * v.x; o.y += am[m] * v.y;
            o.z += am[m] * v.z; o.w += am[m] * v.w;
        }
        *reinterpret_cast<float4*>(dst + d) = o;
    }
}

}  // namespace

extern "C" void kernel_launch(void* const* d_in, const int* in_sizes, int n_in,
                              void* d_out, int out_size, void* d_ws, size_t ws_size,
                              hipStream_t stream) {
    const float* xyz = (const float*)d_in[0];
    const float* W1  = (const float*)d_in[1];
    const float* b1  = (const float*)d_in[2];
    const float* W2  = (const float*)d_in[3];
    const float* b2  = (const float*)d_in[4];
    const float* ipw = (const float*)d_in[5];
    const float* ipb = (const float*)d_in[6];
    const float* opw = (const float*)d_in[7];
    const float* opb = (const float*)d_in[8];

    char* ws = (char*)d_ws;
    float*    A32  = (float*)ws;                   // [65536][96]          25.2 MB
    float*    sqnp = (float*)(ws + 25165824);      // [16384]               64 KB
    int*      cand = (int*)  (ws + 25231360);      // [16384][160]        10.5 MB
    float*    nb   = (float*)(ws + 35717120);      // [16384][96]          6.3 MB
    float*    h1   = (float*)(ws + 42008576);      // [16384][192]        12.6 MB
    ushort*   A16  = (ushort*)(ws + 54591488);     // [16384][96] bf16     3.1 MB
    unsigned* fkey = (unsigned*)(ws + 57737216);   // [16384][160]        10.5 MB
    // MHA phase (cand..fkey dead):
    float*    qkc4  = (float*)(ws + 25231360);     // [65536][192]        50.3 MB
    float*    xmixs = (float*)(ws + 75563008);     // [16384][288]        18.9 MB
    float*    wvo   = (float*)(ws + 94437376);     // [96][288]           110 KB
    float*    b2o   = (float*)(ws + 94547968);     // [96]
    // peak footprint ~94.6 MB (<= the 107 MB verified available in R17)

    for (int h = 0; h < 3; ++h) {
        if (h == 0)
            sqcvt_kernel<true><<<256, 64, 0, stream>>>(xyz, A32, sqnp, A16, 0);
        else
            sqcvt_kernel<false><<<256, 64, 0, stream>>>(A32, A32, sqnp, A16, h);
        knn_mfma_kernel<<<dim3(NPTS / 64, CS), 256, 0, stream>>>(A16, sqnp, cand, fkey);
        rescore_mean_kernel<<<NPTS / 32, 256, 0, stream>>>(A32, sqnp, cand, fkey, nb, h);
        npgemm_kernel<96, true><<<dim3(3, NPTS / 16), dim3(64, 4), 0, stream>>>(
            nb, W1 + (size_t)h * 192 * 96, b1 + h * 192, h1, 192, 192);
        npgemm_kernel<192, false><<<dim3(2, NPTS / 16), dim3(64, 4), 0, stream>>>(
            h1, W2 + (size_t)h * 96 * 192, b2 + h * 96, A32 + (h + 1) * 96, 96, Ll * Cc);
    }

    // MHA: qk-only GEMM + attention-mix + folded (Wv, out-proj) GEMM
    wvo_kernel<<<108, 256, 0, stream>>>(ipw, ipb, opw, opb, wvo, b2o);
    gemm_kernel<96><<<dim3(65536 / 64, 3), 256, 0, stream>>>(
        A32, ipw, ipb, qkc4, 192, 192);
    attnmix_kernel<<<NPTS * 3 / 64, 64, 0, stream>>>(qkc4, A32, xmixs);
    gemm_kernel<288><<<dim3(NPTS / 64, 2), 256, 0, stream>>>(
        xmixs, wvo, b2o, (float*)d_out, 96, 96);
}

// Round 19
// 901.812 us; speedup vs baseline: 1.1349x; 1.1349x over previous
//
#include <hip/hip_runtime.h>
#include <cfloat>

namespace {

constexpr int Bb    = 4;
constexpr int Nn    = 4096;
constexpr int Cc    = 96;
constexpr int Ll    = 4;           // hops+1 slots
constexpr int NPTS  = Bb * Nn;     // 16384
constexpr int KP    = 100;         // padded LDS row stride (floats) for fp32 gemm
constexpr int CS    = 4;           // column splits of the db dimension
constexpr int TK    = 10;          // per-lane candidates (recall bound: 8)
constexpr int NCROW = CS * 4 * TK; // 160 packed keys per row
constexpr int LP    = 104;         // bf16 LDS row pitch (208 B)
constexpr int NSEL  = 24;          // np-rescored survivors of the fast-key merge

typedef __attribute__((ext_vector_type(8))) short bf16x8;
typedef __attribute__((ext_vector_type(4))) float f32x4;

// RNE fp32 -> bf16 (candidate ranking only)
__device__ inline ushort f2bf(float x) {
    unsigned u = __float_as_uint(x);
    return (ushort)((u + 0x7FFF + ((u >> 16) & 1)) >> 16);
}

// lexicographic (value asc, index asc) sorted-insert into top-T
template<int T>
__device__ inline void lexins(float v, int vi, float (&bd)[T], int (&bi)[T]) {
    if (v < bd[T - 1] || (v == bd[T - 1] && vi < bi[T - 1])) {
        #pragma unroll
        for (int t = 0; t < T; ++t) {
            if (v < bd[t] || (v == bd[t] && vi < bi[t])) {
                float tv = bd[t]; bd[t] = v;  v  = tv;
                int   ti = bi[t]; bi[t] = vi; vi = ti;
            }
        }
    }
}

// ---- fused: (optional xyz->A32 slot0 copy) + np-mimic sq (pairwise-8) + bf16 cvt ----
template<bool COPY>
__global__ __launch_bounds__(64) void sqcvt_kernel(const float* __restrict__ src0,
                                                   float* __restrict__ A32,
                                                   float* __restrict__ sqnp,
                                                   ushort* __restrict__ A16, int h) {
    const int p = blockIdx.x * 64 + threadIdx.x;
    const float4* xs = reinterpret_cast<const float4*>(
        COPY ? src0 + (size_t)p * Cc : src0 + (size_t)(p * Ll + h) * Cc);
    float4 x[24];
    #pragma unroll
    for (int i = 0; i < 24; ++i) x[i] = xs[i];
    if (COPY) {
        float4* d = reinterpret_cast<float4*>(A32 + (size_t)p * Ll * Cc);
        #pragma unroll
        for (int i = 0; i < 24; ++i) d[i] = x[i];
    }
    // numpy pairwise-8 tree over fl(x*x)
    float r[8];
    r[0] = __fmul_rn(x[0].x, x[0].x); r[1] = __fmul_rn(x[0].y, x[0].y);
    r[2] = __fmul_rn(x[0].z, x[0].z); r[3] = __fmul_rn(x[0].w, x[0].w);
    r[4] = __fmul_rn(x[1].x, x[1].x); r[5] = __fmul_rn(x[1].y, x[1].y);
    r[6] = __fmul_rn(x[1].z, x[1].z); r[7] = __fmul_rn(x[1].w, x[1].w);
    #pragma unroll
    for (int g = 1; g < 12; ++g) {
        float4 va = x[2 * g], vb = x[2 * g + 1];
        r[0] = __fadd_rn(r[0], __fmul_rn(va.x, va.x));
        r[1] = __fadd_rn(r[1], __fmul_rn(va.y, va.y));
        r[2] = __fadd_rn(r[2], __fmul_rn(va.z, va.z));
        r[3] = __fadd_rn(r[3], __fmul_rn(va.w, va.w));
        r[4] = __fadd_rn(r[4], __fmul_rn(vb.x, vb.x));
        r[5] = __fadd_rn(r[5], __fmul_rn(vb.y, vb.y));
        r[6] = __fadd_rn(r[6], __fmul_rn(vb.z, vb.z));
        r[7] = __fadd_rn(r[7], __fmul_rn(vb.w, vb.w));
    }
    float L = __fadd_rn(__fadd_rn(r[0], r[1]), __fadd_rn(r[2], r[3]));
    float R = __fadd_rn(__fadd_rn(r[4], r[5]), __fadd_rn(r[6], r[7]));
    sqnp[p] = __fadd_rn(L, R);
    #pragma unroll
    for (int j = 0; j < 12; ++j) {
        float4 v0 = x[2 * j], v1 = x[2 * j + 1];
        uint4 o;
        o.x = (unsigned)f2bf(v0.x) | ((unsigned)f2bf(v0.y) << 16);
        o.y = (unsigned)f2bf(v0.z) | ((unsigned)f2bf(v0.w) << 16);
        o.z = (unsigned)f2bf(v1.x) | ((unsigned)f2bf(v1.y) << 16);
        o.w = (unsigned)f2bf(v1.z) | ((unsigned)f2bf(v1.w) << 16);
        *reinterpret_cast<uint4*>(A16 + (size_t)p * 96 + j * 8) = o;
    }
}

// ---- MFMA candidate pass: CS=4, qt/klds LDS union, chunk=64 double-buffer,
// PACKED-KEY scan. Candidate index is FULLY ENCODED by (key pos bits, stream id):
// idx = cs*1024 + c*64 + ((s>>2)<<4) + w*4 + (s&3) — no cand array needed.
// grid (NPTS/64, CS), block 256.
__global__ __launch_bounds__(256) void knn_mfma_kernel(const ushort* __restrict__ A16,
                                                       const float* __restrict__ sqnp,
                                                       unsigned* __restrict__ fkey) {
    __shared__ alignas(16) char uqk[20480];   // union: qt (13312 B) then klds (20480 B)
    __shared__ ushort dbt[2][64 * LP];        // 26624 B
    __shared__ float  sqf[2][64];             //   512 B
    ushort* qt   = (ushort*)uqk;
    float*  klds = (float*)uqk;

    const int q0    = blockIdx.x * 64;
    const int cs    = blockIdx.y;
    const int pbase = (q0 >> 12) << 12;
    const int col0  = cs * (Nn / CS);
    const int tid   = threadIdx.x;
    const int w     = tid >> 6;
    const int l     = tid & 63;
    constexpr int NCH = (Nn / CS) / 64;       // 16 chunks

    {
        int r = tid >> 2, q = tid & 3;
        const uint4* s = reinterpret_cast<const uint4*>(A16 + (size_t)(q0 + r) * 96 + q * 24);
        uint4* d = reinterpret_cast<uint4*>(qt + r * LP + q * 24);
        d[0] = s[0]; d[1] = s[1]; d[2] = s[2];
        const uint4* s2 = reinterpret_cast<const uint4*>(
            A16 + (size_t)(pbase + col0 + r) * 96 + q * 24);
        uint4* d2 = reinterpret_cast<uint4*>(dbt[0] + r * LP + q * 24);
        d2[0] = s2[0]; d2[1] = s2[1]; d2[2] = s2[2];
    }
    if (tid < 64) sqf[0][tid] = -0.5f * sqnp[pbase + col0 + tid];
    __syncthreads();

    const int qrow = w * 16 + (l & 15);
    const int koff = (l >> 4) * 8;
    const int lb4  = (l >> 4) * 4;
    bf16x8 bq[3];
    #pragma unroll
    for (int s = 0; s < 3; ++s)
        bq[s] = *reinterpret_cast<const bf16x8*>(qt + qrow * LP + koff + 32 * s);
    __syncthreads();   // qt reads done before klds (aliased) is written

    unsigned bd[TK];
    #pragma unroll
    for (int t = 0; t < TK; ++t) bd[t] = 0x00800000u;
    float kd = -FLT_MAX;

    for (int c = 0; c < NCH; ++c) {
        const int buf = c & 1;
        if (c + 1 < NCH) {
            int r = tid >> 2, q = tid & 3;
            const uint4* s = reinterpret_cast<const uint4*>(
                A16 + (size_t)(pbase + col0 + (c + 1) * 64 + r) * 96 + q * 24);
            uint4* d = reinterpret_cast<uint4*>(dbt[buf ^ 1] + r * LP + q * 24);
            d[0] = s[0]; d[1] = s[1]; d[2] = s[2];
            if (tid < 64) sqf[buf ^ 1][tid] = -0.5f * sqnp[pbase + col0 + (c + 1) * 64 + tid];
        }

        f32x4 acc[4];
        #pragma unroll
        for (int sub = 0; sub < 4; ++sub) {
            acc[sub] = *reinterpret_cast<const f32x4*>(&sqf[buf][sub * 16 + lb4]);
            #pragma unroll
            for (int s = 0; s < 3; ++s) {
                bf16x8 a = *reinterpret_cast<const bf16x8*>(
                    dbt[buf] + (sub * 16 + (l & 15)) * LP + koff + 32 * s);
                acc[sub] = __builtin_amdgcn_mfma_f32_16x16x32_bf16(a, bq[s], acc[sub], 0, 0, 0);
            }
        }

        unsigned mask = 0;
        #pragma unroll
        for (int sub = 0; sub < 4; ++sub) {
            float m = fmaxf(fmaxf(acc[sub][0], acc[sub][1]),
                            fmaxf(acc[sub][2], acc[sub][3]));
            if (m > kd) {
                *reinterpret_cast<f32x4*>(&klds[tid * 20 + sub * 4]) = acc[sub];
                unsigned mb = (acc[sub][0] > kd ? 1u : 0u) |
                              (acc[sub][1] > kd ? 2u : 0u) |
                              (acc[sub][2] > kd ? 4u : 0u) |
                              (acc[sub][3] > kd ? 8u : 0u);
                mask |= mb << (sub * 4);
            }
        }
        while (mask) {
            int s = __builtin_ctz(mask); mask &= mask - 1;
            float v = klds[tid * 20 + s];
            if (v > kd) {
                unsigned b   = __float_as_uint(v);
                unsigned key = ((b ^ (unsigned)(((int)b >> 31) | 0x80000000)) & ~511u)
                               | (511u - (unsigned)(c * 16 + s));
                #pragma unroll
                for (int t = 0; t < TK; ++t) {
                    unsigned hi = key > bd[t] ? key : bd[t];
                    key         = key > bd[t] ? bd[t] : key;
                    bd[t] = hi;
                }
                unsigned u = bd[TK - 1] & ~511u;
                kd = __uint_as_float((u & 0x80000000u) ? (u ^ 0x80000000u) : ~u);
            }
        }
        __syncthreads();
    }

    const int qg = q0 + qrow;
    const size_t obase = (size_t)qg * NCROW + (cs * 4 + (l >> 4)) * TK;
    #pragma unroll
    for (int t = 0; t < TK; ++t) fkey[obase + t] = bd[t];
}

// ---- decode candidate index from (packed key, flat stream id) ----
__device__ inline int decode_idx(unsigned key, int f) {
    int pos = 511 - (int)(key & 511u);
    int c = pos >> 4, s = pos & 15;
    return (f >> 2) * (Nn / CS) + c * 64 + ((s >> 2) << 4) + (f & 3) * 4 + (s & 3);
}

// ---- np-exact rescore: gather-free packed-key 2-level merge + np mean ----
// Phase 0: load 160 packed keys (640 B/query; NO index array — decoded from key).
// Phase 0b: subs 0-3 merge their cs's 4 streams -> sorted top-12 (parallel).
// Phase 0c: sub 0 merges 4 sorted lists -> top-24 (24x4). Exact (key DESC,
// cand idx ASC): keys unique within a stream; ties across streams/cs resolve
// by ascending scan order == ascending cand idx.
// Phase 1: gather + np-exact rescore the 24 survivors. Phase 2: stable top-8.
// Phase 3: np-mimic mean. block 256 = 32 queries x 8 subs; grid NPTS/32.
__global__ __launch_bounds__(256) void rescore_mean_kernel(const float* __restrict__ A32,
                                                           const float* __restrict__ sqnp,
                                                           const unsigned* __restrict__ fkey,
                                                           float* __restrict__ nb, int h) {
    __shared__ unsigned kly[32][164];           // 16 sorted streams of 10
    __shared__ unsigned m48k[32][48];           // per-cs sorted top-12 keys
    __shared__ unsigned char m48f[32][48];      // their flat stream ids
    __shared__ int      m24[32][NSEL];
    __shared__ float    s24[32][NSEL];
    __shared__ int      sidx[32][8];
    const int tid  = threadIdx.x;
    const int qloc = tid >> 3, sub = tid & 7;
    const int p    = blockIdx.x * 32 + qloc;
    const int base = (p >> 12) << 12;

    // ---- phase 0: keys into LDS (20 per sub = 5 uint4) ----
    {
        const uint4* fs = reinterpret_cast<const uint4*>(fkey + (size_t)p * NCROW + sub * 20);
        #pragma unroll
        for (int m = 0; m < 5; ++m)
            *reinterpret_cast<uint4*>(&kly[qloc][sub * 20 + m * 4]) = fs[m];
    }
    __syncthreads();

    // ---- phase 0b: per-cs 4-way merge -> sorted top-12 (subs 0-3 in parallel) ----
    if (sub < 4) {
        unsigned hp = 0;
        #pragma unroll 1
        for (int t = 0; t < 12; ++t) {
            unsigned bk = 0; int bs = 0; bool any = false;
            #pragma unroll
            for (int s = 0; s < 4; ++s) {
                int hs = (hp >> (4 * s)) & 15;
                if (hs < TK) {
                    unsigned k = kly[qloc][(sub * 4 + s) * TK + hs];
                    if (!any || k > bk) { bk = k; bs = s; any = true; }  // tie: keep lower s
                }
            }
            m48k[qloc][sub * 12 + t] = bk;
            m48f[qloc][sub * 12 + t] = (unsigned char)(sub * 4 + bs);
            hp += 1u << (4 * bs);
        }
    }
    __syncthreads();

    // ---- phase 0c: 4-way merge of sorted-12 lists -> top-24 (sub 0) ----
    if (sub == 0) {
        unsigned hp = 0;
        #pragma unroll 1
        for (int t = 0; t < NSEL; ++t) {
            unsigned bk = 0; int bc = 0, bh = 0; bool any = false;
            #pragma unroll
            for (int c = 0; c < 4; ++c) {
                int hs = (hp >> (4 * c)) & 15;
                if (hs < 12) {
                    unsigned k = m48k[qloc][c * 12 + hs];
                    if (!any || k > bk) { bk = k; bc = c; bh = hs; any = true; }  // tie: lower cs
                }
            }
            m24[qloc][t] = decode_idx(bk, (int)m48f[qloc][bc * 12 + bh]);
            hp += 1u << (4 * bc);
        }
    }
    __syncthreads();

    // ---- phase 1: np-exact rescore of the 24 survivors (3 per sub) ----
    {
        float4 xnr[24];
        const float4* xs = reinterpret_cast<const float4*>(A32 + (size_t)(p * Ll + h) * Cc);
        #pragma unroll
        for (int i = 0; i < 24; ++i) xnr[i] = xs[i];
        const float sqn = sqnp[p];
        #pragma unroll
        for (int c = 0; c < NSEL / 8; ++c) {
            int m = m24[qloc][sub * (NSEL / 8) + c];
            const float4* xm = reinterpret_cast<const float4*>(
                A32 + (size_t)((base + m) * Ll + h) * Cc);
            // np einsum dot: SSE SOP — 4-lane mul+add accumulators, hadd combine
            float l0 = 0.f, l1 = 0.f, l2 = 0.f, l3 = 0.f;
            #pragma unroll
            for (int t = 0; t < 24; ++t) {
                float4 a = xnr[t], b = xm[t];
                l0 = __fadd_rn(l0, __fmul_rn(a.x, b.x));
                l1 = __fadd_rn(l1, __fmul_rn(a.y, b.y));
                l2 = __fadd_rn(l2, __fmul_rn(a.z, b.z));
                l3 = __fadd_rn(l3, __fmul_rn(a.w, b.w));
            }
            float dot = __fadd_rn(__fadd_rn(l0, l1), __fadd_rn(l2, l3));
            // np: d2 = fl(fl(sq_n + sq_m) - fl(2*dot))
            s24[qloc][sub * (NSEL / 8) + c] =
                __fsub_rn(__fadd_rn(sqn, sqnp[base + m]), __fmul_rn(2.0f, dot));
        }
    }
    __syncthreads();

    // ---- phase 2: stable top-8 by (d2, idx) — lax.top_k tie semantics ----
    if (sub == 0) {
        float sd[8]; int si[8];
        #pragma unroll
        for (int t = 0; t < 8; ++t) { sd[t] = FLT_MAX; si[t] = 0x7fffffff; }
        #pragma unroll 1
        for (int c = 0; c < NSEL; ++c) lexins<8>(s24[qloc][c], m24[qloc][c], sd, si);
        #pragma unroll
        for (int t = 0; t < 8; ++t) sidx[qloc][t] = si[t];
    }
    __syncthreads();

    // ---- phase 3: np-mimic mean (pairwise-8 tree, x0.125) ----
    {
        float4 rv[8][3];
        #pragma unroll
        for (int k = 0; k < 8; ++k) {
            const float4* rs = reinterpret_cast<const float4*>(
                A32 + (size_t)((base + sidx[qloc][k]) * Ll + h) * Cc + sub * 12);
            rv[k][0] = rs[0]; rv[k][1] = rs[1]; rv[k][2] = rs[2];
        }
        float4* dst = reinterpret_cast<float4*>(nb + (size_t)p * Cc + sub * 12);
        #pragma unroll
        for (int g = 0; g < 3; ++g) {
            float4 o;
            #define NPMEAN(comp) { \
                float L_ = __fadd_rn(__fadd_rn(rv[0][g].comp, rv[1][g].comp), \
                                     __fadd_rn(rv[2][g].comp, rv[3][g].comp)); \
                float R_ = __fadd_rn(__fadd_rn(rv[4][g].comp, rv[5][g].comp), \
                                     __fadd_rn(rv[6][g].comp, rv[7][g].comp)); \
                o.comp = __fmul_rn(__fadd_rn(L_, R_), 0.125f); }
            NPMEAN(x) NPMEAN(y) NPMEAN(z) NPMEAN(w)
            #undef NPMEAN
            dst[g] = o;
        }
    }
}

// ---- np-mimic MLP GEMM: W staged in LDS once per 16 rows; np FMA chain ----
template<int K, bool LEAKY>
__global__ __launch_bounds__(256) void npgemm_kernel(const float* __restrict__ A,
                                                     const float* __restrict__ W,
                                                     const float* __restrict__ bias,
                                                     float* __restrict__ out,
                                                     int N, int ostride) {
    constexpr int PW = (K == 96) ? 100 : 196;
    __shared__ float w_t[64 * PW];
    const int tx = threadIdx.x, ty = threadIdx.y;
    const int col0 = blockIdx.x * 64;
    const int j = col0 + tx;
    const int i0 = blockIdx.y * 16 + ty * 4;
    {
        int tid = ty * 64 + tx;
        int r = tid >> 2, q = tid & 3;
        constexpr int G = K / 16;
        float4* dst = reinterpret_cast<float4*>(&w_t[r * PW]) + q * G;
        if (col0 + r < N) {
            const float4* src = reinterpret_cast<const float4*>(
                W + (size_t)(col0 + r) * K) + q * G;
            #pragma unroll
            for (int m = 0; m < G; ++m) dst[m] = src[m];
        } else {
            #pragma unroll
            for (int m = 0; m < G; ++m) dst[m] = float4{0.f, 0.f, 0.f, 0.f};
        }
    }
    __syncthreads();
    if (j < N) {
        #pragma unroll
        for (int rr = 0; rr < 4; ++rr) {
            const float* a = A + (size_t)(i0 + rr) * K;
            float acc = 0.f;
            #pragma unroll
            for (int k4 = 0; k4 < K / 4; ++k4) {
                float4 wv = *reinterpret_cast<const float4*>(&w_t[tx * PW + k4 * 4]);
                float4 av = *reinterpret_cast<const float4*>(a + k4 * 4);
                acc = __builtin_fmaf(av.x, wv.x, acc);
                acc = __builtin_fmaf(av.y, wv.y, acc);
                acc = __builtin_fmaf(av.z, wv.z, acc);
                acc = __builtin_fmaf(av.w, wv.w, acc);
            }
            float v = __fadd_rn(acc, bias[j]);
            if (LEAKY) v = v > 0.f ? v : __fmul_rn(0.2f, v);
            out[(size_t)(i0 + rr) * ostride + j] = v;
        }
    }
}

// ---- swizzled fp32 tile staging for value-path gemm ----
__device__ inline void stage_row(const float* __restrict__ src, float* __restrict__ tile,
                                 int r, int q) {
    const int s = (r >> 2) & 7;
    #pragma unroll
    for (int m = 0; m < 6; ++m) {
        int g = q * 6 + m;
        float4 v = reinterpret_cast<const float4*>(src)[g];
        *reinterpret_cast<float4*>(&tile[r * KP + ((g ^ s) << 2)]) = v;
    }
}

// ---------------- fast fp32 GEMM (value path): out = Ain @ W^T + bias ----------------
template<int K>
__global__ __launch_bounds__(256) void gemm_kernel(const float* __restrict__ Ain,
                                                   const float* __restrict__ W,
                                                   const float* __restrict__ bias,
                                                   float* __restrict__ out,
                                                   int Nout, int out_stride) {
    __shared__ float a_t[64 * KP];
    __shared__ float w_t[64 * KP];
    const int row0 = blockIdx.x * 64;
    const int col0 = blockIdx.y * 64;
    const int tid  = threadIdx.x;
    const int tx   = tid & 15;
    const int ty   = tid >> 4;

    float acc[4][4] = {};
    for (int kt = 0; kt < K; kt += 96) {
        __syncthreads();
        {
            int r = tid >> 2, q = tid & 3;
            stage_row(Ain + (size_t)(row0 + r) * K + kt, a_t, r, q);
            if (col0 + r < Nout) {
                stage_row(W + (size_t)(col0 + r) * K + kt, w_t, r, q);
            } else {
                const int s = (r >> 2) & 7;
                #pragma unroll
                for (int m = 0; m < 6; ++m) {
                    int g = q * 6 + m;
                    *reinterpret_cast<float4*>(&w_t[r * KP + ((g ^ s) << 2)]) =
                        float4{0.f, 0.f, 0.f, 0.f};
                }
            }
        }
        __syncthreads();
        const int sa = ty & 7, sb = tx & 7;
        #pragma unroll 4
        for (int k4 = 0; k4 < 24; ++k4) {
            float4 av[4], bv[4];
            const int ga = (k4 ^ sa) << 2, gb = (k4 ^ sb) << 2;
            #pragma unroll
            for (int i = 0; i < 4; ++i)
                av[i] = *reinterpret_cast<const float4*>(&a_t[(ty * 4 + i) * KP + ga]);
            #pragma unroll
            for (int j = 0; j < 4; ++j)
                bv[j] = *reinterpret_cast<const float4*>(&w_t[(tx * 4 + j) * KP + gb]);
            #pragma unroll
            for (int i = 0; i < 4; ++i)
                #pragma unroll
                for (int j = 0; j < 4; ++j)
                    acc[i][j] += av[i].x * bv[j].x + av[i].y * bv[j].y +
                                 av[i].z * bv[j].z + av[i].w * bv[j].w;
        }
    }
    #pragma unroll
    for (int i = 0; i < 4; ++i) {
        int row = row0 + ty * 4 + i;
        #pragma unroll
        for (int j = 0; j < 4; ++j) {
            int col = col0 + tx * 4 + j;
            if (col < Nout)
                out[(size_t)row * out_stride + col] = acc[i][j] + bias[col];
        }
    }
}

// ---- Wvo fold precompute: Wvo[i][h*96+j] = sum_k opw[i][h*32+k]*Wv[h*32+k][j];
// b2o[i] = opb[i] + sum_k opw[i][k]*bv[k].  (Wv = ipw rows 192..287, bv = ipb+192.)
__global__ __launch_bounds__(256) void wvo_kernel(const float* __restrict__ ipw,
                                                  const float* __restrict__ ipb,
                                                  const float* __restrict__ opw,
                                                  const float* __restrict__ opb,
                                                  float* __restrict__ wvo,
                                                  float* __restrict__ b2o) {
    int t = blockIdx.x * 256 + threadIdx.x;          // 96*288 outs
    if (t < 96 * 288) {
        int i = t / 288, hj = t - i * 288;
        int hh = hj / 96, j = hj - hh * 96;
        float acc = 0.f;
        #pragma unroll 8
        for (int k = 0; k < 32; ++k)
            acc = __builtin_fmaf(opw[i * 96 + hh * 32 + k],
                                 ipw[(size_t)(192 + hh * 32 + k) * 96 + j], acc);
        wvo[(size_t)i * 288 + hj] = acc;
    }
    if (t < 96) {
        float acc = opb[t];
        #pragma unroll 8
        for (int k = 0; k < 96; ++k)
            acc = __builtin_fmaf(opw[t * 96 + k], ipb[192 + k], acc);
        b2o[t] = acc;
    }
}

// ---- per-(point, head) attention mix: softmax(q k^T) mean over tokens applied
// directly to the INPUT features x (V/out-proj folded into Wvo downstream).
__global__ __launch_bounds__(64) void attnmix_kernel(const float* __restrict__ qk,
                                                     const float* __restrict__ A32,
                                                     float* __restrict__ xmixs) {
    int t  = blockIdx.x * 64 + threadIdx.x;   // 16384*3
    int p  = t / 3;
    int hh = t - p * 3;
    const float* qb = qk + (size_t)p * 4 * 192 + hh * 32;
    const float* kb = qb + 96;

    float sc[4][4] = {};
    #pragma unroll
    for (int d = 0; d < 32; d += 4) {
        float4 qv[4], kv[4];
        #pragma unroll
        for (int l2 = 0; l2 < 4; ++l2) {
            qv[l2] = *reinterpret_cast<const float4*>(qb + l2 * 192 + d);
            kv[l2] = *reinterpret_cast<const float4*>(kb + l2 * 192 + d);
        }
        #pragma unroll
        for (int l2 = 0; l2 < 4; ++l2)
            #pragma unroll
            for (int m = 0; m < 4; ++m)
                sc[l2][m] += qv[l2].x * kv[m].x + qv[l2].y * kv[m].y +
                             qv[l2].z * kv[m].z + qv[l2].w * kv[m].w;
    }
    const float scale = 0.17677669529663687f;   // 1/sqrt(32)
    float am[4] = {0.f, 0.f, 0.f, 0.f};
    #pragma unroll
    for (int l2 = 0; l2 < 4; ++l2) {
        float s0 = sc[l2][0] * scale, s1 = sc[l2][1] * scale;
        float s2 = sc[l2][2] * scale, s3 = sc[l2][3] * scale;
        float mx = fmaxf(fmaxf(s0, s1), fmaxf(s2, s3));
        float e0 = expf(s0 - mx), e1 = expf(s1 - mx);
        float e2 = expf(s2 - mx), e3 = expf(s3 - mx);
        float inv = 1.f / (e0 + e1 + e2 + e3);
        am[0] += e0 * inv; am[1] += e1 * inv; am[2] += e2 * inv; am[3] += e3 * inv;
    }
    am[0] *= 0.25f; am[1] *= 0.25f; am[2] *= 0.25f; am[3] *= 0.25f;
    const float* xb = A32 + (size_t)p * 4 * 96;
    float* dst = xmixs + (size_t)p * 288 + hh * 96;
    #pragma unroll
    for (int d = 0; d < 96; d += 4) {
        float4 o = {0.f, 0.f, 0.f, 0.f};
        #pragma unroll
        for (int m = 0; m < 4; ++m) {
            float4 v = *reinterpret_cast<const float4*>(xb + m * 96 + d);
            o.x += am[m] * v.x; o.y += am[m] * v.y;
            o.z += am[m] * v.z; o.w += am[m] * v.w;
        }
        *reinterpret_cast<float4*>(dst + d) = o;
    }
}

}  // namespace

extern "C" void kernel_launch(void* const* d_in, const int* in_sizes, int n_in,
                              void* d_out, int out_size, void* d_ws, size_t ws_size,
                              hipStream_t stream) {
    const float* xyz = (const float*)d_in[0];
    const float* W1  = (const float*)d_in[1];
    const float* b1  = (const float*)d_in[2];
    const float* W2  = (const float*)d_in[3];
    const float* b2  = (const float*)d_in[4];
    const float* ipw = (const float*)d_in[5];
    const float* ipb = (const float*)d_in[6];
    const float* opw = (const float*)d_in[7];
    const float* opb = (const float*)d_in[8];

    char* ws = (char*)d_ws;
    float*    A32  = (float*)ws;                   // [65536][96]          25.2 MB
    float*    sqnp = (float*)(ws + 25165824);      // [16384]               64 KB
    unsigned* fkey = (unsigned*)(ws + 25231360);   // [16384][160]        10.5 MB
    float*    nb   = (float*)(ws + 35717120);      // [16384][96]          6.3 MB
    float*    h1   = (float*)(ws + 42008576);      // [16384][192]        12.6 MB
    ushort*   A16  = (ushort*)(ws + 54591488);     // [16384][96] bf16     3.1 MB
    // MHA phase (fkey..A16 dead):
    float*    qkc4  = (float*)(ws + 25231360);     // [65536][192]        50.3 MB
    float*    xmixs = (float*)(ws + 75563008);     // [16384][288]        18.9 MB
    float*    wvo   = (float*)(ws + 94437376);     // [96][288]           110 KB
    float*    b2o   = (float*)(ws + 94547968);     // [96]
    // peak footprint ~94.6 MB

    for (int h = 0; h < 3; ++h) {
        if (h == 0)
            sqcvt_kernel<true><<<256, 64, 0, stream>>>(xyz, A32, sqnp, A16, 0);
        else
            sqcvt_kernel<false><<<256, 64, 0, stream>>>(A32, A32, sqnp, A16, h);
        knn_mfma_kernel<<<dim3(NPTS / 64, CS), 256, 0, stream>>>(A16, sqnp, fkey);
        rescore_mean_kernel<<<NPTS / 32, 256, 0, stream>>>(A32, sqnp, fkey, nb, h);
        npgemm_kernel<96, true><<<dim3(3, NPTS / 16), dim3(64, 4), 0, stream>>>(
            nb, W1 + (size_t)h * 192 * 96, b1 + h * 192, h1, 192, 192);
        npgemm_kernel<192, false><<<dim3(2, NPTS / 16), dim3(64, 4), 0, stream>>>(
            h1, W2 + (size_t)h * 96 * 192, b2 + h * 96, A32 + (h + 1) * 96, 96, Ll * Cc);
    }

    // MHA: qk-only GEMM + attention-mix + folded (Wv, out-proj) GEMM
    wvo_kernel<<<108, 256, 0, stream>>>(ipw, ipb, opw, opb, wvo, b2o);
    gemm_kernel<96><<<dim3(65536 / 64, 3), 256, 0, stream>>>(
        A32, ipw, ipb, qkc4, 192, 192);
    attnmix_kernel<<<NPTS * 3 / 64, 64, 0, stream>>>(qkc4, A32, xmixs);
    gemm_kernel<288><<<dim3(NPTS / 64, 2), 256, 0, stream>>>(
        xmixs, wvo, b2o, (float*)d_out, 96, 96);
}

// Round 20
// 762.810 us; speedup vs baseline: 1.3417x; 1.1822x over previous
//
#include <hip/hip_runtime.h>
#include <cfloat>

namespace {

constexpr int Bb    = 4;
constexpr int Nn    = 4096;
constexpr int Cc    = 96;
constexpr int Ll    = 4;           // hops+1 slots
constexpr int NPTS  = Bb * Nn;     // 16384
constexpr int KP    = 100;         // padded LDS row stride (floats) for fp32 gemm
constexpr int CS    = 4;           // column splits of the db dimension
constexpr int TK    = 10;          // per-lane candidates (recall bound: 8)
constexpr int NCROW = CS * 4 * TK; // 160 packed keys per row
constexpr int LP    = 104;         // bf16 LDS row pitch (208 B)
constexpr int NSEL  = 24;          // np-rescored survivors of the fast-key merge

typedef __attribute__((ext_vector_type(8))) short bf16x8;
typedef __attribute__((ext_vector_type(4))) float f32x4;

// RNE fp32 -> bf16 (candidate ranking only)
__device__ inline ushort f2bf(float x) {
    unsigned u = __float_as_uint(x);
    return (ushort)((u + 0x7FFF + ((u >> 16) & 1)) >> 16);
}

// lexicographic (value asc, index asc) sorted-insert into top-T
template<int T>
__device__ inline void lexins(float v, int vi, float (&bd)[T], int (&bi)[T]) {
    if (v < bd[T - 1] || (v == bd[T - 1] && vi < bi[T - 1])) {
        #pragma unroll
        for (int t = 0; t < T; ++t) {
            if (v < bd[t] || (v == bd[t] && vi < bi[t])) {
                float tv = bd[t]; bd[t] = v;  v  = tv;
                int   ti = bi[t]; bi[t] = vi; vi = ti;
            }
        }
    }
}

// ---- fused: (optional xyz->A32 slot0 copy) + np-mimic sq (pairwise-8) + bf16 cvt ----
template<bool COPY>
__global__ __launch_bounds__(64) void sqcvt_kernel(const float* __restrict__ src0,
                                                   float* __restrict__ A32,
                                                   float* __restrict__ sqnp,
                                                   ushort* __restrict__ A16, int h) {
    const int p = blockIdx.x * 64 + threadIdx.x;
    const float4* xs = reinterpret_cast<const float4*>(
        COPY ? src0 + (size_t)p * Cc : src0 + (size_t)(p * Ll + h) * Cc);
    float4 x[24];
    #pragma unroll
    for (int i = 0; i < 24; ++i) x[i] = xs[i];
    if (COPY) {
        float4* d = reinterpret_cast<float4*>(A32 + (size_t)p * Ll * Cc);
        #pragma unroll
        for (int i = 0; i < 24; ++i) d[i] = x[i];
    }
    // numpy pairwise-8 tree over fl(x*x)
    float r[8];
    r[0] = __fmul_rn(x[0].x, x[0].x); r[1] = __fmul_rn(x[0].y, x[0].y);
    r[2] = __fmul_rn(x[0].z, x[0].z); r[3] = __fmul_rn(x[0].w, x[0].w);
    r[4] = __fmul_rn(x[1].x, x[1].x); r[5] = __fmul_rn(x[1].y, x[1].y);
    r[6] = __fmul_rn(x[1].z, x[1].z); r[7] = __fmul_rn(x[1].w, x[1].w);
    #pragma unroll
    for (int g = 1; g < 12; ++g) {
        float4 va = x[2 * g], vb = x[2 * g + 1];
        r[0] = __fadd_rn(r[0], __fmul_rn(va.x, va.x));
        r[1] = __fadd_rn(r[1], __fmul_rn(va.y, va.y));
        r[2] = __fadd_rn(r[2], __fmul_rn(va.z, va.z));
        r[3] = __fadd_rn(r[3], __fmul_rn(va.w, va.w));
        r[4] = __fadd_rn(r[4], __fmul_rn(vb.x, vb.x));
        r[5] = __fadd_rn(r[5], __fmul_rn(vb.y, vb.y));
        r[6] = __fadd_rn(r[6], __fmul_rn(vb.z, vb.z));
        r[7] = __fadd_rn(r[7], __fmul_rn(vb.w, vb.w));
    }
    float L = __fadd_rn(__fadd_rn(r[0], r[1]), __fadd_rn(r[2], r[3]));
    float R = __fadd_rn(__fadd_rn(r[4], r[5]), __fadd_rn(r[6], r[7]));
    sqnp[p] = __fadd_rn(L, R);
    #pragma unroll
    for (int j = 0; j < 12; ++j) {
        float4 v0 = x[2 * j], v1 = x[2 * j + 1];
        uint4 o;
        o.x = (unsigned)f2bf(v0.x) | ((unsigned)f2bf(v0.y) << 16);
        o.y = (unsigned)f2bf(v0.z) | ((unsigned)f2bf(v0.w) << 16);
        o.z = (unsigned)f2bf(v1.x) | ((unsigned)f2bf(v1.y) << 16);
        o.w = (unsigned)f2bf(v1.z) | ((unsigned)f2bf(v1.w) << 16);
        *reinterpret_cast<uint4*>(A16 + (size_t)p * 96 + j * 8) = o;
    }
}

// ---- MFMA candidate pass: CS=4, qt/klds LDS union, chunk=64 double-buffer,
// PACKED-KEY scan. Candidate index is FULLY ENCODED by (key pos bits, stream id).
// grid (NPTS/64, CS), block 256.
__global__ __launch_bounds__(256) void knn_mfma_kernel(const ushort* __restrict__ A16,
                                                       const float* __restrict__ sqnp,
                                                       unsigned* __restrict__ fkey) {
    __shared__ alignas(16) char uqk[20480];   // union: qt (13312 B) then klds (20480 B)
    __shared__ ushort dbt[2][64 * LP];        // 26624 B
    __shared__ float  sqf[2][64];             //   512 B
    ushort* qt   = (ushort*)uqk;
    float*  klds = (float*)uqk;

    const int q0    = blockIdx.x * 64;
    const int cs    = blockIdx.y;
    const int pbase = (q0 >> 12) << 12;
    const int col0  = cs * (Nn / CS);
    const int tid   = threadIdx.x;
    const int w     = tid >> 6;
    const int l     = tid & 63;
    constexpr int NCH = (Nn / CS) / 64;       // 16 chunks

    {
        int r = tid >> 2, q = tid & 3;
        const uint4* s = reinterpret_cast<const uint4*>(A16 + (size_t)(q0 + r) * 96 + q * 24);
        uint4* d = reinterpret_cast<uint4*>(qt + r * LP + q * 24);
        d[0] = s[0]; d[1] = s[1]; d[2] = s[2];
        const uint4* s2 = reinterpret_cast<const uint4*>(
            A16 + (size_t)(pbase + col0 + r) * 96 + q * 24);
        uint4* d2 = reinterpret_cast<uint4*>(dbt[0] + r * LP + q * 24);
        d2[0] = s2[0]; d2[1] = s2[1]; d2[2] = s2[2];
    }
    if (tid < 64) sqf[0][tid] = -0.5f * sqnp[pbase + col0 + tid];
    __syncthreads();

    const int qrow = w * 16 + (l & 15);
    const int koff = (l >> 4) * 8;
    const int lb4  = (l >> 4) * 4;
    bf16x8 bq[3];
    #pragma unroll
    for (int s = 0; s < 3; ++s)
        bq[s] = *reinterpret_cast<const bf16x8*>(qt + qrow * LP + koff + 32 * s);
    __syncthreads();   // qt reads done before klds (aliased) is written

    unsigned bd[TK];
    #pragma unroll
    for (int t = 0; t < TK; ++t) bd[t] = 0x00800000u;
    float kd = -FLT_MAX;

    for (int c = 0; c < NCH; ++c) {
        const int buf = c & 1;
        if (c + 1 < NCH) {
            int r = tid >> 2, q = tid & 3;
            const uint4* s = reinterpret_cast<const uint4*>(
                A16 + (size_t)(pbase + col0 + (c + 1) * 64 + r) * 96 + q * 24);
            uint4* d = reinterpret_cast<uint4*>(dbt[buf ^ 1] + r * LP + q * 24);
            d[0] = s[0]; d[1] = s[1]; d[2] = s[2];
            if (tid < 64) sqf[buf ^ 1][tid] = -0.5f * sqnp[pbase + col0 + (c + 1) * 64 + tid];
        }

        f32x4 acc[4];
        #pragma unroll
        for (int sub = 0; sub < 4; ++sub) {
            acc[sub] = *reinterpret_cast<const f32x4*>(&sqf[buf][sub * 16 + lb4]);
            #pragma unroll
            for (int s = 0; s < 3; ++s) {
                bf16x8 a = *reinterpret_cast<const bf16x8*>(
                    dbt[buf] + (sub * 16 + (l & 15)) * LP + koff + 32 * s);
                acc[sub] = __builtin_amdgcn_mfma_f32_16x16x32_bf16(a, bq[s], acc[sub], 0, 0, 0);
            }
        }

        unsigned mask = 0;
        #pragma unroll
        for (int sub = 0; sub < 4; ++sub) {
            float m = fmaxf(fmaxf(acc[sub][0], acc[sub][1]),
                            fmaxf(acc[sub][2], acc[sub][3]));
            if (m > kd) {
                *reinterpret_cast<f32x4*>(&klds[tid * 20 + sub * 4]) = acc[sub];
                unsigned mb = (acc[sub][0] > kd ? 1u : 0u) |
                              (acc[sub][1] > kd ? 2u : 0u) |
                              (acc[sub][2] > kd ? 4u : 0u) |
                              (acc[sub][3] > kd ? 8u : 0u);
                mask |= mb << (sub * 4);
            }
        }
        while (mask) {
            int s = __builtin_ctz(mask); mask &= mask - 1;
            float v = klds[tid * 20 + s];
            if (v > kd) {
                unsigned b   = __float_as_uint(v);
                unsigned key = ((b ^ (unsigned)(((int)b >> 31) | 0x80000000)) & ~511u)
                               | (511u - (unsigned)(c * 16 + s));
                #pragma unroll
                for (int t = 0; t < TK; ++t) {
                    unsigned hi = key > bd[t] ? key : bd[t];
                    key         = key > bd[t] ? bd[t] : key;
                    bd[t] = hi;
                }
                unsigned u = bd[TK - 1] & ~511u;
                kd = __uint_as_float((u & 0x80000000u) ? (u ^ 0x80000000u) : ~u);
            }
        }
        __syncthreads();
    }

    const int qg = q0 + qrow;
    const size_t obase = (size_t)qg * NCROW + (cs * 4 + (l >> 4)) * TK;
    #pragma unroll
    for (int t = 0; t < TK; ++t) fkey[obase + t] = bd[t];
}

// ---- decode candidate index from (packed key, flat stream id) ----
__device__ inline int decode_idx(unsigned key, int f) {
    int pos = 511 - (int)(key & 511u);
    int c = pos >> 4, s = pos & 15;
    return (f >> 2) * (Nn / CS) + c * 64 + ((s >> 2) << 4) + (f & 3) * 4 + (s & 3);
}

// ---- np-exact rescore: gather-free packed-key 2-level merge + np mean ----
// block 256 = 32 queries x 8 subs; grid NPTS/32.
__global__ __launch_bounds__(256) void rescore_mean_kernel(const float* __restrict__ A32,
                                                           const float* __restrict__ sqnp,
                                                           const unsigned* __restrict__ fkey,
                                                           float* __restrict__ nb, int h) {
    __shared__ unsigned kly[32][164];           // 16 sorted streams of 10
    __shared__ unsigned m48k[32][48];           // per-cs sorted top-12 keys
    __shared__ unsigned char m48f[32][48];      // their flat stream ids
    __shared__ int      m24[32][NSEL];
    __shared__ float    s24[32][NSEL];
    __shared__ int      sidx[32][8];
    const int tid  = threadIdx.x;
    const int qloc = tid >> 3, sub = tid & 7;
    const int p    = blockIdx.x * 32 + qloc;
    const int base = (p >> 12) << 12;

    // ---- phase 0: keys into LDS (20 per sub = 5 uint4) ----
    {
        const uint4* fs = reinterpret_cast<const uint4*>(fkey + (size_t)p * NCROW + sub * 20);
        #pragma unroll
        for (int m = 0; m < 5; ++m)
            *reinterpret_cast<uint4*>(&kly[qloc][sub * 20 + m * 4]) = fs[m];
    }
    __syncthreads();

    // ---- phase 0b: per-cs 4-way merge -> sorted top-12 (subs 0-3 in parallel) ----
    if (sub < 4) {
        unsigned hp = 0;
        #pragma unroll 1
        for (int t = 0; t < 12; ++t) {
            unsigned bk = 0; int bs = 0; bool any = false;
            #pragma unroll
            for (int s = 0; s < 4; ++s) {
                int hs = (hp >> (4 * s)) & 15;
                if (hs < TK) {
                    unsigned k = kly[qloc][(sub * 4 + s) * TK + hs];
                    if (!any || k > bk) { bk = k; bs = s; any = true; }  // tie: keep lower s
                }
            }
            m48k[qloc][sub * 12 + t] = bk;
            m48f[qloc][sub * 12 + t] = (unsigned char)(sub * 4 + bs);
            hp += 1u << (4 * bs);
        }
    }
    __syncthreads();

    // ---- phase 0c: 4-way merge of sorted-12 lists -> top-24 (sub 0) ----
    if (sub == 0) {
        unsigned hp = 0;
        #pragma unroll 1
        for (int t = 0; t < NSEL; ++t) {
            unsigned bk = 0; int bc = 0, bh = 0; bool any = false;
            #pragma unroll
            for (int c = 0; c < 4; ++c) {
                int hs = (hp >> (4 * c)) & 15;
                if (hs < 12) {
                    unsigned k = m48k[qloc][c * 12 + hs];
                    if (!any || k > bk) { bk = k; bc = c; bh = hs; any = true; }  // tie: lower cs
                }
            }
            m24[qloc][t] = decode_idx(bk, (int)m48f[qloc][bc * 12 + bh]);
            hp += 1u << (4 * bc);
        }
    }
    __syncthreads();

    // ---- phase 1: np-exact rescore of the 24 survivors (3 per sub) ----
    {
        float4 xnr[24];
        const float4* xs = reinterpret_cast<const float4*>(A32 + (size_t)(p * Ll + h) * Cc);
        #pragma unroll
        for (int i = 0; i < 24; ++i) xnr[i] = xs[i];
        const float sqn = sqnp[p];
        #pragma unroll
        for (int c = 0; c < NSEL / 8; ++c) {
            int m = m24[qloc][sub * (NSEL / 8) + c];
            const float4* xm = reinterpret_cast<const float4*>(
                A32 + (size_t)((base + m) * Ll + h) * Cc);
            // np einsum dot: SSE SOP — 4-lane mul+add accumulators, hadd combine
            float l0 = 0.f, l1 = 0.f, l2 = 0.f, l3 = 0.f;
            #pragma unroll
            for (int t = 0; t < 24; ++t) {
                float4 a = xnr[t], b = xm[t];
                l0 = __fadd_rn(l0, __fmul_rn(a.x, b.x));
                l1 = __fadd_rn(l1, __fmul_rn(a.y, b.y));
                l2 = __fadd_rn(l2, __fmul_rn(a.z, b.z));
                l3 = __fadd_rn(l3, __fmul_rn(a.w, b.w));
            }
            float dot = __fadd_rn(__fadd_rn(l0, l1), __fadd_rn(l2, l3));
            // np: d2 = fl(fl(sq_n + sq_m) - fl(2*dot))
            s24[qloc][sub * (NSEL / 8) + c] =
                __fsub_rn(__fadd_rn(sqn, sqnp[base + m]), __fmul_rn(2.0f, dot));
        }
    }
    __syncthreads();

    // ---- phase 2: stable top-8 by (d2, idx) — lax.top_k tie semantics ----
    if (sub == 0) {
        float sd[8]; int si[8];
        #pragma unroll
        for (int t = 0; t < 8; ++t) { sd[t] = FLT_MAX; si[t] = 0x7fffffff; }
        #pragma unroll 1
        for (int c = 0; c < NSEL; ++c) lexins<8>(s24[qloc][c], m24[qloc][c], sd, si);
        #pragma unroll
        for (int t = 0; t < 8; ++t) sidx[qloc][t] = si[t];
    }
    __syncthreads();

    // ---- phase 3: np-mimic mean (pairwise-8 tree, x0.125) ----
    {
        float4 rv[8][3];
        #pragma unroll
        for (int k = 0; k < 8; ++k) {
            const float4* rs = reinterpret_cast<const float4*>(
                A32 + (size_t)((base + sidx[qloc][k]) * Ll + h) * Cc + sub * 12);
            rv[k][0] = rs[0]; rv[k][1] = rs[1]; rv[k][2] = rs[2];
        }
        float4* dst = reinterpret_cast<float4*>(nb + (size_t)p * Cc + sub * 12);
        #pragma unroll
        for (int g = 0; g < 3; ++g) {
            float4 o;
            #define NPMEAN(comp) { \
                float L_ = __fadd_rn(__fadd_rn(rv[0][g].comp, rv[1][g].comp), \
                                     __fadd_rn(rv[2][g].comp, rv[3][g].comp)); \
                float R_ = __fadd_rn(__fadd_rn(rv[4][g].comp, rv[5][g].comp), \
                                     __fadd_rn(rv[6][g].comp, rv[7][g].comp)); \
                o.comp = __fmul_rn(__fadd_rn(L_, R_), 0.125f); }
            NPMEAN(x) NPMEAN(y) NPMEAN(z) NPMEAN(w)
            #undef NPMEAN
            dst[g] = o;
        }
    }
}

// ---- np-mimic MLP GEMM: out = act(A @ W^T + bias); BLAS-style sequential-k FMA.
// W tile in LDS with XOR-swizzled granules (8-way read conflict -> ~2-way: lane
// tx's row stride PW===4 mod 32 put tx and tx+8 on one bank). The 4 row-chains
// are INTERLEAVED per k4 for 4x ILP; each output's FMA chain order is
// bit-identical to the scalar np reference. grid (ceil(N/64), M/16), block (64,4).
template<int K, bool LEAKY>
__global__ __launch_bounds__(256) void npgemm_kernel(const float* __restrict__ A,
                                                     const float* __restrict__ W,
                                                     const float* __restrict__ bias,
                                                     float* __restrict__ out,
                                                     int N, int ostride) {
    constexpr int PW = (K == 96) ? 100 : 196;   // padded row stride (16B-aligned rows)
    __shared__ float w_t[64 * PW];
    const int tx = threadIdx.x, ty = threadIdx.y;
    const int col0 = blockIdx.x * 64;
    const int j = col0 + tx;
    const int i0 = blockIdx.y * 16 + ty * 4;    // 4 consecutive rows per thread
    {
        int tid = ty * 64 + tx;
        int r = tid >> 2, q = tid & 3;
        constexpr int G = K / 16;               // float4 granules per quarter-thread
        const int s = r & 7;
        if (col0 + r < N) {
            const float4* src = reinterpret_cast<const float4*>(
                W + (size_t)(col0 + r) * K) + q * G;
            #pragma unroll
            for (int m = 0; m < G; ++m) {
                int g = q * G + m;
                *reinterpret_cast<float4*>(&w_t[r * PW + ((g ^ s) << 2)]) = src[m];
            }
        } else {
            #pragma unroll
            for (int m = 0; m < G; ++m) {
                int g = q * G + m;
                *reinterpret_cast<float4*>(&w_t[r * PW + ((g ^ s) << 2)]) =
                    float4{0.f, 0.f, 0.f, 0.f};
            }
        }
    }
    __syncthreads();
    if (j < N) {
        const float* a0 = A + (size_t)i0 * K;   // 4 wave-uniform rows
        const int sx = tx & 7;
        float acc0 = 0.f, acc1 = 0.f, acc2 = 0.f, acc3 = 0.f;
        #pragma unroll
        for (int k4 = 0; k4 < K / 4; ++k4) {
            float4 wv = *reinterpret_cast<const float4*>(&w_t[tx * PW + ((k4 ^ sx) << 2)]);
            float4 a_0 = *reinterpret_cast<const float4*>(a0 + k4 * 4);
            float4 a_1 = *reinterpret_cast<const float4*>(a0 + K + k4 * 4);
            float4 a_2 = *reinterpret_cast<const float4*>(a0 + 2 * K + k4 * 4);
            float4 a_3 = *reinterpret_cast<const float4*>(a0 + 3 * K + k4 * 4);
            acc0 = __builtin_fmaf(a_0.x, wv.x, acc0);
            acc1 = __builtin_fmaf(a_1.x, wv.x, acc1);
            acc2 = __builtin_fmaf(a_2.x, wv.x, acc2);
            acc3 = __builtin_fmaf(a_3.x, wv.x, acc3);
            acc0 = __builtin_fmaf(a_0.y, wv.y, acc0);
            acc1 = __builtin_fmaf(a_1.y, wv.y, acc1);
            acc2 = __builtin_fmaf(a_2.y, wv.y, acc2);
            acc3 = __builtin_fmaf(a_3.y, wv.y, acc3);
            acc0 = __builtin_fmaf(a_0.z, wv.z, acc0);
            acc1 = __builtin_fmaf(a_1.z, wv.z, acc1);
            acc2 = __builtin_fmaf(a_2.z, wv.z, acc2);
            acc3 = __builtin_fmaf(a_3.z, wv.z, acc3);
            acc0 = __builtin_fmaf(a_0.w, wv.w, acc0);
            acc1 = __builtin_fmaf(a_1.w, wv.w, acc1);
            acc2 = __builtin_fmaf(a_2.w, wv.w, acc2);
            acc3 = __builtin_fmaf(a_3.w, wv.w, acc3);
        }
        const float bj = bias[j];
        float v0 = __fadd_rn(acc0, bj), v1 = __fadd_rn(acc1, bj);
        float v2 = __fadd_rn(acc2, bj), v3 = __fadd_rn(acc3, bj);
        if (LEAKY) {
            v0 = v0 > 0.f ? v0 : __fmul_rn(0.2f, v0);
            v1 = v1 > 0.f ? v1 : __fmul_rn(0.2f, v1);
            v2 = v2 > 0.f ? v2 : __fmul_rn(0.2f, v2);
            v3 = v3 > 0.f ? v3 : __fmul_rn(0.2f, v3);
        }
        out[(size_t)i0 * ostride + j] = v0;
        out[(size_t)(i0 + 1) * ostride + j] = v1;
        out[(size_t)(i0 + 2) * ostride + j] = v2;
        out[(size_t)(i0 + 3) * ostride + j] = v3;
    }
}

// ---- swizzled fp32 tile staging for value-path gemm ----
__device__ inline void stage_row(const float* __restrict__ src, float* __restrict__ tile,
                                 int r, int q) {
    const int s = (r >> 2) & 7;
    #pragma unroll
    for (int m = 0; m < 6; ++m) {
        int g = q * 6 + m;
        float4 v = reinterpret_cast<const float4*>(src)[g];
        *reinterpret_cast<float4*>(&tile[r * KP + ((g ^ s) << 2)]) = v;
    }
}

// ---------------- fast fp32 GEMM (value path): out = Ain @ W^T + bias ----------------
template<int K>
__global__ __launch_bounds__(256) void gemm_kernel(const float* __restrict__ Ain,
                                                   const float* __restrict__ W,
                                                   const float* __restrict__ bias,
                                                   float* __restrict__ out,
                                                   int Nout, int out_stride) {
    __shared__ float a_t[64 * KP];
    __shared__ float w_t[64 * KP];
    const int row0 = blockIdx.x * 64;
    const int col0 = blockIdx.y * 64;
    const int tid  = threadIdx.x;
    const int tx   = tid & 15;
    const int ty   = tid >> 4;

    float acc[4][4] = {};
    for (int kt = 0; kt < K; kt += 96) {
        __syncthreads();
        {
            int r = tid >> 2, q = tid & 3;
            stage_row(Ain + (size_t)(row0 + r) * K + kt, a_t, r, q);
            if (col0 + r < Nout) {
                stage_row(W + (size_t)(col0 + r) * K + kt, w_t, r, q);
            } else {
                const int s = (r >> 2) & 7;
                #pragma unroll
                for (int m = 0; m < 6; ++m) {
                    int g = q * 6 + m;
                    *reinterpret_cast<float4*>(&w_t[r * KP + ((g ^ s) << 2)]) =
                        float4{0.f, 0.f, 0.f, 0.f};
                }
            }
        }
        __syncthreads();
        const int sa = ty & 7, sb = tx & 7;
        #pragma unroll 4
        for (int k4 = 0; k4 < 24; ++k4) {
            float4 av[4], bv[4];
            const int ga = (k4 ^ sa) << 2, gb = (k4 ^ sb) << 2;
            #pragma unroll
            for (int i = 0; i < 4; ++i)
                av[i] = *reinterpret_cast<const float4*>(&a_t[(ty * 4 + i) * KP + ga]);
            #pragma unroll
            for (int j = 0; j < 4; ++j)
                bv[j] = *reinterpret_cast<const float4*>(&w_t[(tx * 4 + j) * KP + gb]);
            #pragma unroll
            for (int i = 0; i < 4; ++i)
                #pragma unroll
                for (int j = 0; j < 4; ++j)
                    acc[i][j] += av[i].x * bv[j].x + av[i].y * bv[j].y +
                                 av[i].z * bv[j].z + av[i].w * bv[j].w;
        }
    }
    #pragma unroll
    for (int i = 0; i < 4; ++i) {
        int row = row0 + ty * 4 + i;
        #pragma unroll
        for (int j = 0; j < 4; ++j) {
            int col = col0 + tx * 4 + j;
            if (col < Nout)
                out[(size_t)row * out_stride + col] = acc[i][j] + bias[col];
        }
    }
}

// ---- Wvo fold precompute: Wvo[i][h*96+j] = sum_k opw[i][h*32+k]*Wv[h*32+k][j];
// b2o[i] = opb[i] + sum_k opw[i][k]*bv[k].  (Wv = ipw rows 192..287, bv = ipb+192.)
__global__ __launch_bounds__(256) void wvo_kernel(const float* __restrict__ ipw,
                                                  const float* __restrict__ ipb,
                                                  const float* __restrict__ opw,
                                                  const float* __restrict__ opb,
                                                  float* __restrict__ wvo,
                                                  float* __restrict__ b2o) {
    int t = blockIdx.x * 256 + threadIdx.x;          // 96*288 outs
    if (t < 96 * 288) {
        int i = t / 288, hj = t - i * 288;
        int hh = hj / 96, j = hj - hh * 96;
        float acc = 0.f;
        #pragma unroll 8
        for (int k = 0; k < 32; ++k)
            acc = __builtin_fmaf(opw[i * 96 + hh * 32 + k],
                                 ipw[(size_t)(192 + hh * 32 + k) * 96 + j], acc);
        wvo[(size_t)i * 288 + hj] = acc;
    }
    if (t < 96) {
        float acc = opb[t];
        #pragma unroll 8
        for (int k = 0; k < 96; ++k)
            acc = __builtin_fmaf(opw[t * 96 + k], ipb[192 + k], acc);
        b2o[t] = acc;
    }
}

// ---- per-(point, head) attention mix: softmax(q k^T) mean over tokens applied
// directly to the INPUT features x (V/out-proj folded into Wvo downstream).
__global__ __launch_bounds__(64) void attnmix_kernel(const float* __restrict__ qk,
                                                     const float* __restrict__ A32,
                                                     float* __restrict__ xmixs) {
    int t  = blockIdx.x * 64 + threadIdx.x;   // 16384*3
    int p  = t / 3;
    int hh = t - p * 3;
    const float* qb = qk + (size_t)p * 4 * 192 + hh * 32;
    const float* kb = qb + 96;

    float sc[4][4] = {};
    #pragma unroll
    for (int d = 0; d < 32; d += 4) {
        float4 qv[4], kv[4];
        #pragma unroll
        for (int l2 = 0; l2 < 4; ++l2) {
            qv[l2] = *reinterpret_cast<const float4*>(qb + l2 * 192 + d);
            kv[l2] = *reinterpret_cast<const float4*>(kb + l2 * 192 + d);
        }
        #pragma unroll
        for (int l2 = 0; l2 < 4; ++l2)
            #pragma unroll
            for (int m = 0; m < 4; ++m)
                sc[l2][m] += qv[l2].x * kv[m].x + qv[l2].y * kv[m].y +
                             qv[l2].z * kv[m].z + qv[l2].w * kv[m].w;
    }
    const float scale = 0.17677669529663687f;   // 1/sqrt(32)
    float am[4] = {0.f, 0.f, 0.f, 0.f};
    #pragma unroll
    for (int l2 = 0; l2 < 4; ++l2) {
        float s0 = sc[l2][0] * scale, s1 = sc[l2][1] * scale;
        float s2 = sc[l2][2] * scale, s3 = sc[l2][3] * scale;
        float mx = fmaxf(fmaxf(s0, s1), fmaxf(s2, s3));
        float e0 = expf(s0 - mx), e1 = expf(s1 - mx);
        float e2 = expf(s2 - mx), e3 = expf(s3 - mx);
        float inv = 1.f / (e0 + e1 + e2 + e3);
        am[0] += e0 * inv; am[1] += e1 * inv; am[2] += e2 * inv; am[3] += e3 * inv;
    }
    am[0] *= 0.25f; am[1] *= 0.25f; am[2] *= 0.25f; am[3] *= 0.25f;
    const float* xb = A32 + (size_t)p * 4 * 96;
    float* dst = xmixs + (size_t)p * 288 + hh * 96;
    #pragma unroll
    for (int d = 0; d < 96; d += 4) {
        float4 o = {0.f, 0.f, 0.f, 0.f};
        #pragma unroll
        for (int m = 0; m < 4; ++m) {
            float4 v = *reinterpret_cast<const float4*>(xb + m * 96 + d);
            o.x += am[m] * v.x; o.y += am[m] * v.y;
            o.z += am[m] * v.z; o.w += am[m] * v.w;
        }
        *reinterpret_cast<float4*>(dst + d) = o;
    }
}

}  // namespace

extern "C" void kernel_launch(void* const* d_in, const int* in_sizes, int n_in,
                              void* d_out, int out_size, void* d_ws, size_t ws_size,
                              hipStream_t stream) {
    const float* xyz = (const float*)d_in[0];
    const float* W1  = (const float*)d_in[1];
    const float* b1  = (const float*)d_in[2];
    const float* W2  = (const float*)d_in[3];
    const float* b2  = (const float*)d_in[4];
    const float* ipw = (const float*)d_in[5];
    const float* ipb = (const float*)d_in[6];
    const float* opw = (const float*)d_in[7];
    const float* opb = (const float*)d_in[8];

    char* ws = (char*)d_ws;
    float*    A32  = (float*)ws;                   // [65536][96]          25.2 MB
    float*    sqnp = (float*)(ws + 25165824);      // [16384]               64 KB
    unsigned* fkey = (unsigned*)(ws + 25231360);   // [16384][160]        10.5 MB
    float*    nb   = (float*)(ws + 35717120);      // [16384][96]          6.3 MB
    float*    h1   = (float*)(ws + 42008576);      // [16384][192]        12.6 MB
    ushort*   A16  = (ushort*)(ws + 54591488);     // [16384][96] bf16     3.1 MB
    // MHA phase (fkey..A16 dead):
    float*    qkc4  = (float*)(ws + 25231360);     // [65536][192]        50.3 MB
    float*    xmixs = (float*)(ws + 75563008);     // [16384][288]        18.9 MB
    float*    wvo   = (float*)(ws + 94437376);     // [96][288]           110 KB
    float*    b2o   = (float*)(ws + 94547968);     // [96]
    // peak footprint ~94.6 MB

    for (int h = 0; h < 3; ++h) {
        if (h == 0)
            sqcvt_kernel<true><<<256, 64, 0, stream>>>(xyz, A32, sqnp, A16, 0);
        else
            sqcvt_kernel<false><<<256, 64, 0, stream>>>(A32, A32, sqnp, A16, h);
        knn_mfma_kernel<<<dim3(NPTS / 64, CS), 256, 0, stream>>>(A16, sqnp, fkey);
        rescore_mean_kernel<<<NPTS / 32, 256, 0, stream>>>(A32, sqnp, fkey, nb, h);
        npgemm_kernel<96, true><<<dim3(3, NPTS / 16), dim3(64, 4), 0, stream>>>(
            nb, W1 + (size_t)h * 192 * 96, b1 + h * 192, h1, 192, 192);
        npgemm_kernel<192, false><<<dim3(2, NPTS / 16), dim3(64, 4), 0, stream>>>(
            h1, W2 + (size_t)h * 96 * 192, b2 + h * 96, A32 + (h + 1) * 96, 96, Ll * Cc);
    }

    // MHA: qk-only GEMM + attention-mix + folded (Wv, out-proj) GEMM
    wvo_kernel<<<108, 256, 0, stream>>>(ipw, ipb, opw, opb, wvo, b2o);
    gemm_kernel<96><<<dim3(65536 / 64, 3), 256, 0, stream>>>(
        A32, ipw, ipb, qkc4, 192, 192);
    attnmix_kernel<<<NPTS * 3 / 64, 64, 0, stream>>>(qkc4, A32, xmixs);
    gemm_kernel<288><<<dim3(NPTS / 64, 2), 256, 0, stream>>>(
        xmixs, wvo, b2o, (float*)d_out, 96, 96);
}

// Round 21
// 728.928 us; speedup vs baseline: 1.4040x; 1.0465x over previous
//
#include <hip/hip_runtime.h>
#include <cfloat>

namespace {

constexpr int Bb    = 4;
constexpr int Nn    = 4096;
constexpr int Cc    = 96;
constexpr int Ll    = 4;           // hops+1 slots
constexpr int NPTS  = Bb * Nn;     // 16384
constexpr int KP    = 100;         // padded LDS row stride (floats) for fp32 gemm
constexpr int CS    = 4;           // column splits of the db dimension
constexpr int TK    = 10;          // per-lane candidates (recall bound: 8)
constexpr int NCROW = CS * 4 * TK; // 160 packed keys per row
constexpr int LP    = 104;         // bf16 LDS row pitch (208 B)
constexpr int NSEL  = 24;          // np-rescored survivors of the fast-key merge

typedef __attribute__((ext_vector_type(8))) short bf16x8;
typedef __attribute__((ext_vector_type(4))) float f32x4;

// RNE fp32 -> bf16 (candidate ranking only)
__device__ inline ushort f2bf(float x) {
    unsigned u = __float_as_uint(x);
    return (ushort)((u + 0x7FFF + ((u >> 16) & 1)) >> 16);
}

// lexicographic (value asc, index asc) sorted-insert into top-T
template<int T>
__device__ inline void lexins(float v, int vi, float (&bd)[T], int (&bi)[T]) {
    if (v < bd[T - 1] || (v == bd[T - 1] && vi < bi[T - 1])) {
        #pragma unroll
        for (int t = 0; t < T; ++t) {
            if (v < bd[t] || (v == bd[t] && vi < bi[t])) {
                float tv = bd[t]; bd[t] = v;  v  = tv;
                int   ti = bi[t]; bi[t] = vi; vi = ti;
            }
        }
    }
}

// ---- fused: (optional xyz->A32 slot0 copy) + np-mimic sq (pairwise-8) + bf16 cvt ----
template<bool COPY>
__global__ __launch_bounds__(64) void sqcvt_kernel(const float* __restrict__ src0,
                                                   float* __restrict__ A32,
                                                   float* __restrict__ sqnp,
                                                   ushort* __restrict__ A16, int h) {
    const int p = blockIdx.x * 64 + threadIdx.x;
    const float4* xs = reinterpret_cast<const float4*>(
        COPY ? src0 + (size_t)p * Cc : src0 + (size_t)(p * Ll + h) * Cc);
    float4 x[24];
    #pragma unroll
    for (int i = 0; i < 24; ++i) x[i] = xs[i];
    if (COPY) {
        float4* d = reinterpret_cast<float4*>(A32 + (size_t)p * Ll * Cc);
        #pragma unroll
        for (int i = 0; i < 24; ++i) d[i] = x[i];
    }
    // numpy pairwise-8 tree over fl(x*x)
    float r[8];
    r[0] = __fmul_rn(x[0].x, x[0].x); r[1] = __fmul_rn(x[0].y, x[0].y);
    r[2] = __fmul_rn(x[0].z, x[0].z); r[3] = __fmul_rn(x[0].w, x[0].w);
    r[4] = __fmul_rn(x[1].x, x[1].x); r[5] = __fmul_rn(x[1].y, x[1].y);
    r[6] = __fmul_rn(x[1].z, x[1].z); r[7] = __fmul_rn(x[1].w, x[1].w);
    #pragma unroll
    for (int g = 1; g < 12; ++g) {
        float4 va = x[2 * g], vb = x[2 * g + 1];
        r[0] = __fadd_rn(r[0], __fmul_rn(va.x, va.x));
        r[1] = __fadd_rn(r[1], __fmul_rn(va.y, va.y));
        r[2] = __fadd_rn(r[2], __fmul_rn(va.z, va.z));
        r[3] = __fadd_rn(r[3], __fmul_rn(va.w, va.w));
        r[4] = __fadd_rn(r[4], __fmul_rn(vb.x, vb.x));
        r[5] = __fadd_rn(r[5], __fmul_rn(vb.y, vb.y));
        r[6] = __fadd_rn(r[6], __fmul_rn(vb.z, vb.z));
        r[7] = __fadd_rn(r[7], __fmul_rn(vb.w, vb.w));
    }
    float L = __fadd_rn(__fadd_rn(r[0], r[1]), __fadd_rn(r[2], r[3]));
    float R = __fadd_rn(__fadd_rn(r[4], r[5]), __fadd_rn(r[6], r[7]));
    sqnp[p] = __fadd_rn(L, R);
    #pragma unroll
    for (int j = 0; j < 12; ++j) {
        float4 v0 = x[2 * j], v1 = x[2 * j + 1];
        uint4 o;
        o.x = (unsigned)f2bf(v0.x) | ((unsigned)f2bf(v0.y) << 16);
        o.y = (unsigned)f2bf(v0.z) | ((unsigned)f2bf(v0.w) << 16);
        o.z = (unsigned)f2bf(v1.x) | ((unsigned)f2bf(v1.y) << 16);
        o.w = (unsigned)f2bf(v1.z) | ((unsigned)f2bf(v1.w) << 16);
        *reinterpret_cast<uint4*>(A16 + (size_t)p * 96 + j * 8) = o;
    }
}

// ---- MFMA candidate pass: CS=4, SINGLE LDS buffer + register prefetch
// (3 uint4/thread — small enough to stay in VGPRs, unlike R13's 6).
// LDS 34 KB -> 4 blocks/CU, matching the 1024-block grid co-residency.
// acc init = -sq/2 -> s = dot - sq/2 (d2 asc == s DESC). PACKED-KEY scan.
// grid (NPTS/64, CS), block 256.
__global__ __launch_bounds__(256) void knn_mfma_kernel(const ushort* __restrict__ A16,
                                                       const float* __restrict__ sqnp,
                                                       unsigned* __restrict__ fkey) {
    __shared__ alignas(16) char uqk[20480];   // union: qt (13312 B) then klds (20480 B)
    __shared__ ushort dbt[64 * LP];           // 13312 B (single buffer)
    __shared__ float  sqf[64];                //   256 B
    ushort* qt   = (ushort*)uqk;
    float*  klds = (float*)uqk;

    const int q0    = blockIdx.x * 64;
    const int cs    = blockIdx.y;
    const int pbase = (q0 >> 12) << 12;
    const int col0  = cs * (Nn / CS);
    const int tid   = threadIdx.x;
    const int w     = tid >> 6;
    const int l     = tid & 63;
    constexpr int NCH = (Nn / CS) / 64;       // 16 chunks
    const int r4 = tid >> 2, q4 = tid & 3;    // staging partition: 4 thr/row, 3 uint4

    {   // stage Q tile + chunk 0
        const uint4* s = reinterpret_cast<const uint4*>(A16 + (size_t)(q0 + r4) * 96 + q4 * 24);
        uint4* d = reinterpret_cast<uint4*>(qt + r4 * LP + q4 * 24);
        d[0] = s[0]; d[1] = s[1]; d[2] = s[2];
        const uint4* s2 = reinterpret_cast<const uint4*>(
            A16 + (size_t)(pbase + col0 + r4) * 96 + q4 * 24);
        uint4* d2 = reinterpret_cast<uint4*>(dbt + r4 * LP + q4 * 24);
        d2[0] = s2[0]; d2[1] = s2[1]; d2[2] = s2[2];
    }
    if (tid < 64) sqf[tid] = -0.5f * sqnp[pbase + col0 + tid];
    __syncthreads();

    const int qrow = w * 16 + (l & 15);
    const int koff = (l >> 4) * 8;
    const int lb4  = (l >> 4) * 4;
    bf16x8 bq[3];
    #pragma unroll
    for (int s = 0; s < 3; ++s)
        bq[s] = *reinterpret_cast<const bf16x8*>(qt + qrow * LP + koff + 32 * s);
    __syncthreads();   // qt reads done before klds (aliased) is written

    unsigned bd[TK];
    #pragma unroll
    for (int t = 0; t < TK; ++t) bd[t] = 0x00800000u;
    float kd = -FLT_MAX;

    for (int c = 0; c < NCH; ++c) {
        // issue next chunk's loads into registers (latency hides under MFMA+scan)
        uint4 pf0, pf1, pf2; float sqpf = 0.f;
        const bool hasNext = (c + 1 < NCH);
        if (hasNext) {
            const uint4* s = reinterpret_cast<const uint4*>(
                A16 + (size_t)(pbase + col0 + (c + 1) * 64 + r4) * 96 + q4 * 24);
            pf0 = s[0]; pf1 = s[1]; pf2 = s[2];
            if (tid < 64) sqpf = sqnp[pbase + col0 + (c + 1) * 64 + tid];
        }

        f32x4 acc[4];
        #pragma unroll
        for (int sub = 0; sub < 4; ++sub) {
            acc[sub] = *reinterpret_cast<const f32x4*>(&sqf[sub * 16 + lb4]);
            #pragma unroll
            for (int s = 0; s < 3; ++s) {
                bf16x8 a = *reinterpret_cast<const bf16x8*>(
                    dbt + (sub * 16 + (l & 15)) * LP + koff + 32 * s);
                acc[sub] = __builtin_amdgcn_mfma_f32_16x16x32_bf16(a, bq[s], acc[sub], 0, 0, 0);
            }
        }
        // acc[sub][3] is from sqf[sub*16+lb4+3]... (per-lane row class; mapping as R20)

        unsigned mask = 0;
        #pragma unroll
        for (int sub = 0; sub < 4; ++sub) {
            float m = fmaxf(fmaxf(acc[sub][0], acc[sub][1]),
                            fmaxf(acc[sub][2], acc[sub][3]));
            if (m > kd) {
                *reinterpret_cast<f32x4*>(&klds[tid * 20 + sub * 4]) = acc[sub];
                unsigned mb = (acc[sub][0] > kd ? 1u : 0u) |
                              (acc[sub][1] > kd ? 2u : 0u) |
                              (acc[sub][2] > kd ? 4u : 0u) |
                              (acc[sub][3] > kd ? 8u : 0u);
                mask |= mb << (sub * 4);
            }
        }
        while (mask) {
            int s = __builtin_ctz(mask); mask &= mask - 1;
            float v = klds[tid * 20 + s];
            if (v > kd) {
                unsigned b   = __float_as_uint(v);
                unsigned key = ((b ^ (unsigned)(((int)b >> 31) | 0x80000000)) & ~511u)
                               | (511u - (unsigned)(c * 16 + s));
                #pragma unroll
                for (int t = 0; t < TK; ++t) {
                    unsigned hi = key > bd[t] ? key : bd[t];
                    key         = key > bd[t] ? bd[t] : key;
                    bd[t] = hi;
                }
                unsigned u = bd[TK - 1] & ~511u;
                kd = __uint_as_float((u & 0x80000000u) ? (u ^ 0x80000000u) : ~u);
            }
        }
        __syncthreads();   // all reads of dbt/sqf done
        if (hasNext) {
            uint4* d = reinterpret_cast<uint4*>(dbt + r4 * LP + q4 * 24);
            d[0] = pf0; d[1] = pf1; d[2] = pf2;
            if (tid < 64) sqf[tid] = -0.5f * sqpf;
        }
        __syncthreads();   // next chunk staged
    }

    const int qg = q0 + qrow;
    const size_t obase = (size_t)qg * NCROW + (cs * 4 + (l >> 4)) * TK;
    #pragma unroll
    for (int t = 0; t < TK; ++t) fkey[obase + t] = bd[t];
}

// ---- decode candidate index from (packed key, flat stream id) ----
__device__ inline int decode_idx(unsigned key, int f) {
    int pos = 511 - (int)(key & 511u);
    int c = pos >> 4, s = pos & 15;
    return (f >> 2) * (Nn / CS) + c * 64 + ((s >> 2) << 4) + (f & 3) * 4 + (s & 3);
}

// ---- np-exact rescore: gather-free packed-key 2-level merge + np mean ----
// block 256 = 32 queries x 8 subs; grid NPTS/32.
__global__ __launch_bounds__(256) void rescore_mean_kernel(const float* __restrict__ A32,
                                                           const float* __restrict__ sqnp,
                                                           const unsigned* __restrict__ fkey,
                                                           float* __restrict__ nb, int h) {
    __shared__ unsigned kly[32][164];           // 16 sorted streams of 10
    __shared__ unsigned m48k[32][48];           // per-cs sorted top-12 keys
    __shared__ unsigned char m48f[32][48];      // their flat stream ids
    __shared__ int      m24[32][NSEL];
    __shared__ float    s24[32][NSEL];
    __shared__ int      sidx[32][8];
    const int tid  = threadIdx.x;
    const int qloc = tid >> 3, sub = tid & 7;
    const int p    = blockIdx.x * 32 + qloc;
    const int base = (p >> 12) << 12;

    // ---- phase 0: keys into LDS (20 per sub = 5 uint4) ----
    {
        const uint4* fs = reinterpret_cast<const uint4*>(fkey + (size_t)p * NCROW + sub * 20);
        #pragma unroll
        for (int m = 0; m < 5; ++m)
            *reinterpret_cast<uint4*>(&kly[qloc][sub * 20 + m * 4]) = fs[m];
    }
    __syncthreads();

    // ---- phase 0b: per-cs 4-way merge -> sorted top-12 (subs 0-3 in parallel) ----
    if (sub < 4) {
        unsigned hp = 0;
        #pragma unroll 1
        for (int t = 0; t < 12; ++t) {
            unsigned bk = 0; int bs = 0; bool any = false;
            #pragma unroll
            for (int s = 0; s < 4; ++s) {
                int hs = (hp >> (4 * s)) & 15;
                if (hs < TK) {
                    unsigned k = kly[qloc][(sub * 4 + s) * TK + hs];
                    if (!any || k > bk) { bk = k; bs = s; any = true; }  // tie: keep lower s
                }
            }
            m48k[qloc][sub * 12 + t] = bk;
            m48f[qloc][sub * 12 + t] = (unsigned char)(sub * 4 + bs);
            hp += 1u << (4 * bs);
        }
    }
    __syncthreads();

    // ---- phase 0c: 4-way merge of sorted-12 lists -> top-24 (sub 0) ----
    if (sub == 0) {
        unsigned hp = 0;
        #pragma unroll 1
        for (int t = 0; t < NSEL; ++t) {
            unsigned bk = 0; int bc = 0, bh = 0; bool any = false;
            #pragma unroll
            for (int c = 0; c < 4; ++c) {
                int hs = (hp >> (4 * c)) & 15;
                if (hs < 12) {
                    unsigned k = m48k[qloc][c * 12 + hs];
                    if (!any || k > bk) { bk = k; bc = c; bh = hs; any = true; }  // tie: lower cs
                }
            }
            m24[qloc][t] = decode_idx(bk, (int)m48f[qloc][bc * 12 + bh]);
            hp += 1u << (4 * bc);
        }
    }
    __syncthreads();

    // ---- phase 1: np-exact rescore of the 24 survivors (3 per sub) ----
    {
        float4 xnr[24];
        const float4* xs = reinterpret_cast<const float4*>(A32 + (size_t)(p * Ll + h) * Cc);
        #pragma unroll
        for (int i = 0; i < 24; ++i) xnr[i] = xs[i];
        const float sqn = sqnp[p];
        #pragma unroll
        for (int c = 0; c < NSEL / 8; ++c) {
            int m = m24[qloc][sub * (NSEL / 8) + c];
            const float4* xm = reinterpret_cast<const float4*>(
                A32 + (size_t)((base + m) * Ll + h) * Cc);
            // np einsum dot: SSE SOP — 4-lane mul+add accumulators, hadd combine
            float l0 = 0.f, l1 = 0.f, l2 = 0.f, l3 = 0.f;
            #pragma unroll
            for (int t = 0; t < 24; ++t) {
                float4 a = xnr[t], b = xm[t];
                l0 = __fadd_rn(l0, __fmul_rn(a.x, b.x));
                l1 = __fadd_rn(l1, __fmul_rn(a.y, b.y));
                l2 = __fadd_rn(l2, __fmul_rn(a.z, b.z));
                l3 = __fadd_rn(l3, __fmul_rn(a.w, b.w));
            }
            float dot = __fadd_rn(__fadd_rn(l0, l1), __fadd_rn(l2, l3));
            // np: d2 = fl(fl(sq_n + sq_m) - fl(2*dot))
            s24[qloc][sub * (NSEL / 8) + c] =
                __fsub_rn(__fadd_rn(sqn, sqnp[base + m]), __fmul_rn(2.0f, dot));
        }
    }
    __syncthreads();

    // ---- phase 2: stable top-8 by (d2, idx) — lax.top_k tie semantics ----
    if (sub == 0) {
        float sd[8]; int si[8];
        #pragma unroll
        for (int t = 0; t < 8; ++t) { sd[t] = FLT_MAX; si[t] = 0x7fffffff; }
        #pragma unroll 1
        for (int c = 0; c < NSEL; ++c) lexins<8>(s24[qloc][c], m24[qloc][c], sd, si);
        #pragma unroll
        for (int t = 0; t < 8; ++t) sidx[qloc][t] = si[t];
    }
    __syncthreads();

    // ---- phase 3: np-mimic mean (pairwise-8 tree, x0.125) ----
    {
        float4 rv[8][3];
        #pragma unroll
        for (int k = 0; k < 8; ++k) {
            const float4* rs = reinterpret_cast<const float4*>(
                A32 + (size_t)((base + sidx[qloc][k]) * Ll + h) * Cc + sub * 12);
            rv[k][0] = rs[0]; rv[k][1] = rs[1]; rv[k][2] = rs[2];
        }
        float4* dst = reinterpret_cast<float4*>(nb + (size_t)p * Cc + sub * 12);
        #pragma unroll
        for (int g = 0; g < 3; ++g) {
            float4 o;
            #define NPMEAN(comp) { \
                float L_ = __fadd_rn(__fadd_rn(rv[0][g].comp, rv[1][g].comp), \
                                     __fadd_rn(rv[2][g].comp, rv[3][g].comp)); \
                float R_ = __fadd_rn(__fadd_rn(rv[4][g].comp, rv[5][g].comp), \
                                     __fadd_rn(rv[6][g].comp, rv[7][g].comp)); \
                o.comp = __fmul_rn(__fadd_rn(L_, R_), 0.125f); }
            NPMEAN(x) NPMEAN(y) NPMEAN(z) NPMEAN(w)
            #undef NPMEAN
            dst[g] = o;
        }
    }
}

// ---- np-mimic MLP GEMM: K staged in 96-wide chunks (PW=100 -> LDS 25.6 KB,
// ~2x occupancy for K=192). XOR-swizzled granules; 4 interleaved row-chains.
// Each output's FMA chain order (k ascending) bit-identical to scalar np ref.
// grid (ceil(N/64), M/16), block (64,4).
template<int K, bool LEAKY>
__global__ __launch_bounds__(256) void npgemm_kernel(const float* __restrict__ A,
                                                     const float* __restrict__ W,
                                                     const float* __restrict__ bias,
                                                     float* __restrict__ out,
                                                     int N, int ostride) {
    constexpr int PW = 100;
    __shared__ float w_t[64 * PW];
    const int tx = threadIdx.x, ty = threadIdx.y;
    const int col0 = blockIdx.x * 64;
    const int j = col0 + tx;
    const int i0 = blockIdx.y * 16 + ty * 4;    // 4 consecutive rows per thread
    const int tid = ty * 64 + tx;
    const int r = tid >> 2, q = tid & 3;
    const int sw = r & 7;
    const int sx = tx & 7;
    const float* a0 = A + (size_t)i0 * K;
    float acc0 = 0.f, acc1 = 0.f, acc2 = 0.f, acc3 = 0.f;

    for (int kt = 0; kt < K; kt += 96) {
        __syncthreads();   // previous chunk reads done
        if (col0 + r < N) {
            const float4* src = reinterpret_cast<const float4*>(
                W + (size_t)(col0 + r) * K + kt) + q * 6;
            #pragma unroll
            for (int m = 0; m < 6; ++m) {
                int g = q * 6 + m;
                *reinterpret_cast<float4*>(&w_t[r * PW + ((g ^ sw) << 2)]) = src[m];
            }
        } else {
            #pragma unroll
            for (int m = 0; m < 6; ++m) {
                int g = q * 6 + m;
                *reinterpret_cast<float4*>(&w_t[r * PW + ((g ^ sw) << 2)]) =
                    float4{0.f, 0.f, 0.f, 0.f};
            }
        }
        __syncthreads();
        if (j < N) {
            #pragma unroll
            for (int k4 = 0; k4 < 24; ++k4) {
                float4 wv = *reinterpret_cast<const float4*>(
                    &w_t[tx * PW + ((k4 ^ sx) << 2)]);
                float4 a_0 = *reinterpret_cast<const float4*>(a0 + kt + k4 * 4);
                float4 a_1 = *reinterpret_cast<const float4*>(a0 + K + kt + k4 * 4);
                float4 a_2 = *reinterpret_cast<const float4*>(a0 + 2 * K + kt + k4 * 4);
                float4 a_3 = *reinterpret_cast<const float4*>(a0 + 3 * K + kt + k4 * 4);
                acc0 = __builtin_fmaf(a_0.x, wv.x, acc0);
                acc1 = __builtin_fmaf(a_1.x, wv.x, acc1);
                acc2 = __builtin_fmaf(a_2.x, wv.x, acc2);
                acc3 = __builtin_fmaf(a_3.x, wv.x, acc3);
                acc0 = __builtin_fmaf(a_0.y, wv.y, acc0);
                acc1 = __builtin_fmaf(a_1.y, wv.y, acc1);
                acc2 = __builtin_fmaf(a_2.y, wv.y, acc2);
                acc3 = __builtin_fmaf(a_3.y, wv.y, acc3);
                acc0 = __builtin_fmaf(a_0.z, wv.z, acc0);
                acc1 = __builtin_fmaf(a_1.z, wv.z, acc1);
                acc2 = __builtin_fmaf(a_2.z, wv.z, acc2);
                acc3 = __builtin_fmaf(a_3.z, wv.z, acc3);
                acc0 = __builtin_fmaf(a_0.w, wv.w, acc0);
                acc1 = __builtin_fmaf(a_1.w, wv.w, acc1);
                acc2 = __builtin_fmaf(a_2.w, wv.w, acc2);
                acc3 = __builtin_fmaf(a_3.w, wv.w, acc3);
            }
        }
    }
    if (j < N) {
        const float bj = bias[j];
        float v0 = __fadd_rn(acc0, bj), v1 = __fadd_rn(acc1, bj);
        float v2 = __fadd_rn(acc2, bj), v3 = __fadd_rn(acc3, bj);
        if (LEAKY) {
            v0 = v0 > 0.f ? v0 : __fmul_rn(0.2f, v0);
            v1 = v1 > 0.f ? v1 : __fmul_rn(0.2f, v1);
            v2 = v2 > 0.f ? v2 : __fmul_rn(0.2f, v2);
            v3 = v3 > 0.f ? v3 : __fmul_rn(0.2f, v3);
        }
        out[(size_t)i0 * ostride + j] = v0;
        out[(size_t)(i0 + 1) * ostride + j] = v1;
        out[(size_t)(i0 + 2) * ostride + j] = v2;
        out[(size_t)(i0 + 3) * ostride + j] = v3;
    }
}

// ---- swizzled fp32 tile staging for value-path gemm ----
__device__ inline void stage_row(const float* __restrict__ src, float* __restrict__ tile,
                                 int r, int q) {
    const int s = (r >> 2) & 7;
    #pragma unroll
    for (int m = 0; m < 6; ++m) {
        int g = q * 6 + m;
        float4 v = reinterpret_cast<const float4*>(src)[g];
        *reinterpret_cast<float4*>(&tile[r * KP + ((g ^ s) << 2)]) = v;
    }
}

// ---------------- fast fp32 GEMM (value path): out = Ain @ W^T + bias ----------------
template<int K>
__global__ __launch_bounds__(256) void gemm_kernel(const float* __restrict__ Ain,
                                                   const float* __restrict__ W,
                                                   const float* __restrict__ bias,
                                                   float* __restrict__ out,
                                                   int Nout, int out_stride) {
    __shared__ float a_t[64 * KP];
    __shared__ float w_t[64 * KP];
    const int row0 = blockIdx.x * 64;
    const int col0 = blockIdx.y * 64;
    const int tid  = threadIdx.x;
    const int tx   = tid & 15;
    const int ty   = tid >> 4;

    float acc[4][4] = {};
    for (int kt = 0; kt < K; kt += 96) {
        __syncthreads();
        {
            int r = tid >> 2, q = tid & 3;
            stage_row(Ain + (size_t)(row0 + r) * K + kt, a_t, r, q);
            if (col0 + r < Nout) {
                stage_row(W + (size_t)(col0 + r) * K + kt, w_t, r, q);
            } else {
                const int s = (r >> 2) & 7;
                #pragma unroll
                for (int m = 0; m < 6; ++m) {
                    int g = q * 6 + m;
                    *reinterpret_cast<float4*>(&w_t[r * KP + ((g ^ s) << 2)]) =
                        float4{0.f, 0.f, 0.f, 0.f};
                }
            }
        }
        __syncthreads();
        const int sa = ty & 7, sb = tx & 7;
        #pragma unroll 4
        for (int k4 = 0; k4 < 24; ++k4) {
            float4 av[4], bv[4];
            const int ga = (k4 ^ sa) << 2, gb = (k4 ^ sb) << 2;
            #pragma unroll
            for (int i = 0; i < 4; ++i)
                av[i] = *reinterpret_cast<const float4*>(&a_t[(ty * 4 + i) * KP + ga]);
            #pragma unroll
            for (int j = 0; j < 4; ++j)
                bv[j] = *reinterpret_cast<const float4*>(&w_t[(tx * 4 + j) * KP + gb]);
            #pragma unroll
            for (int i = 0; i < 4; ++i)
                #pragma unroll
                for (int j = 0; j < 4; ++j)
                    acc[i][j] += av[i].x * bv[j].x + av[i].y * bv[j].y +
                                 av[i].z * bv[j].z + av[i].w * bv[j].w;
        }
    }
    #pragma unroll
    for (int i = 0; i < 4; ++i) {
        int row = row0 + ty * 4 + i;
        #pragma unroll
        for (int j = 0; j < 4; ++j) {
            int col = col0 + tx * 4 + j;
            if (col < Nout)
                out[(size_t)row * out_stride + col] = acc[i][j] + bias[col];
        }
    }
}

// ---- Wvo fold precompute: Wvo[i][h*96+j] = sum_k opw[i][h*32+k]*Wv[h*32+k][j];
// b2o[i] = opb[i] + sum_k opw[i][k]*bv[k].  (Wv = ipw rows 192..287, bv = ipb+192.)
__global__ __launch_bounds__(256) void wvo_kernel(const float* __restrict__ ipw,
                                                  const float* __restrict__ ipb,
                                                  const float* __restrict__ opw,
                                                  const float* __restrict__ opb,
                                                  float* __restrict__ wvo,
                                                  float* __restrict__ b2o) {
    int t = blockIdx.x * 256 + threadIdx.x;          // 96*288 outs
    if (t < 96 * 288) {
        int i = t / 288, hj = t - i * 288;
        int hh = hj / 96, j = hj - hh * 96;
        float acc = 0.f;
        #pragma unroll 8
        for (int k = 0; k < 32; ++k)
            acc = __builtin_fmaf(opw[i * 96 + hh * 32 + k],
                                 ipw[(size_t)(192 + hh * 32 + k) * 96 + j], acc);
        wvo[(size_t)i * 288 + hj] = acc;
    }
    if (t < 96) {
        float acc = opb[t];
        #pragma unroll 8
        for (int k = 0; k < 96; ++k)
            acc = __builtin_fmaf(opw[t * 96 + k], ipb[192 + k], acc);
        b2o[t] = acc;
    }
}

// ---- per-(point, head) attention mix: softmax(q k^T) mean over tokens applied
// directly to the INPUT features x (V/out-proj folded into Wvo downstream).
__global__ __launch_bounds__(64) void attnmix_kernel(const float* __restrict__ qk,
                                                     const float* __restrict__ A32,
                                                     float* __restrict__ xmixs) {
    int t  = blockIdx.x * 64 + threadIdx.x;   // 16384*3
    int p  = t / 3;
    int hh = t - p * 3;
    const float* qb = qk + (size_t)p * 4 * 192 + hh * 32;
    const float* kb = qb + 96;

    float sc[4][4] = {};
    #pragma unroll
    for (int d = 0; d < 32; d += 4) {
        float4 qv[4], kv[4];
        #pragma unroll
        for (int l2 = 0; l2 < 4; ++l2) {
            qv[l2] = *reinterpret_cast<const float4*>(qb + l2 * 192 + d);
            kv[l2] = *reinterpret_cast<const float4*>(kb + l2 * 192 + d);
        }
        #pragma unroll
        for (int l2 = 0; l2 < 4; ++l2)
            #pragma unroll
            for (int m = 0; m < 4; ++m)
                sc[l2][m] += qv[l2].x * kv[m].x + qv[l2].y * kv[m].y +
                             qv[l2].z * kv[m].z + qv[l2].w * kv[m].w;
    }
    const float scale = 0.17677669529663687f;   // 1/sqrt(32)
    float am[4] = {0.f, 0.f, 0.f, 0.f};
    #pragma unroll
    for (int l2 = 0; l2 < 4; ++l2) {
        float s0 = sc[l2][0] * scale, s1 = sc[l2][1] * scale;
        float s2 = sc[l2][2] * scale, s3 = sc[l2][3] * scale;
        float mx = fmaxf(fmaxf(s0, s1), fmaxf(s2, s3));
        float e0 = expf(s0 - mx), e1 = expf(s1 - mx);
        float e2 = expf(s2 - mx), e3 = expf(s3 - mx);
        float inv = 1.f / (e0 + e1 + e2 + e3);
        am[0] += e0 * inv; am[1] += e1 * inv; am[2] += e2 * inv; am[3] += e3 * inv;
    }
    am[0] *= 0.25f; am[1] *= 0.25f; am[2] *= 0.25f; am[3] *= 0.25f;
    const float* xb = A32 + (size_t)p * 4 * 96;
    float* dst = xmixs + (size_t)p * 288 + hh * 96;
    #pragma unroll
    for (int d = 0; d < 96; d += 4) {
        float4 o = {0.f, 0.f, 0.f, 0.f};
        #pragma unroll
        for (int m = 0; m < 4; ++m) {
            float4 v = *reinterpret_cast<const float4*>(xb + m * 96 + d);
            o.x += am[m] * v.x; o.y += am[m] * v.y;
            o.z += am[m] * v.z; o.w += am[m] * v.w;
        }
        *reinterpret_cast<float4*>(dst + d) = o;
    }
}

}  // namespace

extern "C" void kernel_launch(void* const* d_in, const int* in_sizes, int n_in,
                              void* d_out, int out_size, void* d_ws, size_t ws_size,
                              hipStream_t stream) {
    const float* xyz = (const float*)d_in[0];
    const float* W1  = (const float*)d_in[1];
    const float* b1  = (const float*)d_in[2];
    const float* W2  = (const float*)d_in[3];
    const float* b2  = (const float*)d_in[4];
    const float* ipw = (const float*)d_in[5];
    const float* ipb = (const float*)d_in[6];
    const float* opw = (const float*)d_in[7];
    const float* opb = (const float*)d_in[8];

    char* ws = (char*)d_ws;
    float*    A32  = (float*)ws;                   // [65536][96]          25.2 MB
    float*    sqnp = (float*)(ws + 25165824);      // [16384]               64 KB
    unsigned* fkey = (unsigned*)(ws + 25231360);   // [16384][160]        10.5 MB
    float*    nb   = (float*)(ws + 35717120);      // [16384][96]          6.3 MB
    float*    h1   = (float*)(ws + 42008576);      // [16384][192]        12.6 MB
    ushort*   A16  = (ushort*)(ws + 54591488);     // [16384][96] bf16     3.1 MB
    // MHA phase (fkey..A16 dead):
    float*    qkc4  = (float*)(ws + 25231360);     // [65536][192]        50.3 MB
    float*    xmixs = (float*)(ws + 75563008);     // [16384][288]        18.9 MB
    float*    wvo   = (float*)(ws + 94437376);     // [96][288]           110 KB
    float*    b2o   = (float*)(ws + 94547968);     // [96]
    // peak footprint ~94.6 MB

    for (int h = 0; h < 3; ++h) {
        if (h == 0)
            sqcvt_kernel<true><<<256, 64, 0, stream>>>(xyz, A32, sqnp, A16, 0);
        else
            sqcvt_kernel<false><<<256, 64, 0, stream>>>(A32, A32, sqnp, A16, h);
        knn_mfma_kernel<<<dim3(NPTS / 64, CS), 256, 0, stream>>>(A16, sqnp, fkey);
        rescore_mean_kernel<<<NPTS / 32, 256, 0, stream>>>(A32, sqnp, fkey, nb, h);
        npgemm_kernel<96, true><<<dim3(3, NPTS / 16), dim3(64, 4), 0, stream>>>(
            nb, W1 + (size_t)h * 192 * 96, b1 + h * 192, h1, 192, 192);
        npgemm_kernel<192, false><<<dim3(2, NPTS / 16), dim3(64, 4), 0, stream>>>(
            h1, W2 + (size_t)h * 96 * 192, b2 + h * 96, A32 + (h + 1) * 96, 96, Ll * Cc);
    }

    // MHA: qk-only GEMM + attention-mix + folded (Wv, out-proj) GEMM
    wvo_kernel<<<108, 256, 0, stream>>>(ipw, ipb, opw, opb, wvo, b2o);
    gemm_kernel<96><<<dim3(65536 / 64, 3), 256, 0, stream>>>(
        A32, ipw, ipb, qkc4, 192, 192);
    attnmix_kernel<<<NPTS * 3 / 64, 64, 0, stream>>>(qkc4, A32, xmixs);
    gemm_kernel<288><<<dim3(NPTS / 64, 2), 256, 0, stream>>>(
        xmixs, wvo, b2o, (float*)d_out, 96, 96);
}